// Round 1
// baseline (1820.535 us; speedup 1.0000x reference)
//
#include <hip/hip_runtime.h>
#include <cstdint>
#include <math.h>

// ConvDBN: 2-layer conv-RBM with Gumbel-max multinomial pooling.
// Numerics: l1 exact f64 (h1 must stay exact); l2 main path PURE f32
// accumulation (R15) + exact-f64 TAU redo. R12's per-ic f64 fold is gone:
// f32 full-sum error eps~2e-5 -> decision noise 50*eps ~1e-3 << TAU=6e-3,
// so unflagged winners == f64 winners and flagged outputs are redone exactly
// from h1_f64 -> final argmax decisions bit-identical to R12/R14 scheme.
// RNG: JAX threefry2x32 partitionable split, 32-bit draw = o0^o1.
// R15 theory: R14's 64-VGPR codegen (f64 accs = 36 regs live) forced the
// compiler to re-stream w[49]/xr from LDS -> LDS pipe ~saturated and
// SQ_LDS_BANK_CONFLICT=2.22e8 (~34% of CU cycles). Dropping the f64 accs
// frees ~40 VGPR so w[49]+xr[12]+c0/c1 stay register-resident (expect
// VGPR ~96-128), and hs row stride 38->40 makes reads exactly 2-way
// (f mod 32 = 24bh+8PR+6c+2k: {0,24,16,8}+{0,6,12,18} = 16 banks x 2 lanes,
// free per m136; other half-wave = same addr broadcast). Row base
// 120bh+6(sp&3) even -> float2 = ds_read_b64 kept: 54 hs + 25 w reads/chunk.
// Padding breaks DMA -> register-staged double-buffer (coverage: 4x256=1024
// >= 900, 2x256=512 >= 392 -- audited, the R10/R11 bug class). init folded
// into l1. Spill sentinel: WRITE_SIZE (~3.2 MB = output only expected).

#define EPS_D 1e-8
#define INV_SIGMA2 (1.0 / (0.2 * 0.2))
#define TAU 6e-3
#define REDO_CAP 32768
#define H1_BYTES (5529600ull * 8ull)
#define H1F32_BYTES (5529600ull * 4ull)

__host__ __device__ __forceinline__ void threefry2x32(
    uint32_t k0, uint32_t k1, uint32_t x0, uint32_t x1,
    uint32_t* o0, uint32_t* o1) {
  const uint32_t ks0 = k0, ks1 = k1, ks2 = k0 ^ k1 ^ 0x1BD11BDAu;
  x0 += ks0; x1 += ks1;
#define TF_R(r) { x0 += x1; x1 = (x1 << (r)) | (x1 >> (32 - (r))); x1 ^= x0; }
  TF_R(13) TF_R(15) TF_R(26) TF_R(6)
  x0 += ks1; x1 += ks2 + 1u;
  TF_R(17) TF_R(29) TF_R(16) TF_R(24)
  x0 += ks2; x1 += ks0 + 2u;
  TF_R(13) TF_R(15) TF_R(26) TF_R(6)
  x0 += ks0; x1 += ks1 + 3u;
  TF_R(17) TF_R(29) TF_R(16) TF_R(24)
  x0 += ks1; x1 += ks2 + 4u;
  TF_R(13) TF_R(15) TF_R(26) TF_R(6)
  x0 += ks2; x1 += ks0 + 5u;
#undef TF_R
  *o0 = x0; *o1 = x1;
}

__device__ __forceinline__ double fast_log(double x) {
  long long ib = __double_as_longlong(x);
  int e = (int)((ib >> 52) & 0x7ff) - 1023;
  double r = __longlong_as_double((ib & 0xfffffffffffffLL) | 0x3ff0000000000000LL);
  if (r > 1.4142135623730951) { r *= 0.5; e += 1; }
  double s = (r - 1.0) / (r + 1.0);
  double s2 = s * s;
  double t = fma(s2, fma(s2, fma(s2, fma(s2, fma(s2, fma(s2,
      1.0/15.0, 1.0/13.0), 1.0/11.0), 1.0/9.0), 1.0/7.0), 1.0/5.0), 1.0/3.0);
  double lr = fma(2.0 * s * s2, t, 2.0 * s);
  return fma((double)e, 0.6931471805599453, lr);
}

__device__ __forceinline__ double fast_exp(double x) {
  double nd = rint(x * 1.4426950408889634);
  double f = fma(nd, -0.6931471803691238, x);
  f = fma(nd, -1.9082149292705877e-10, f);
  double p = 2.505210838544172e-8;
  p = fma(p, f, 2.755731922398589e-7);
  p = fma(p, f, 2.7557319223985893e-6);
  p = fma(p, f, 2.48015873015873e-5);
  p = fma(p, f, 1.984126984126984e-4);
  p = fma(p, f, 1.3888888888888889e-3);
  p = fma(p, f, 8.333333333333333e-3);
  p = fma(p, f, 4.1666666666666664e-2);
  p = fma(p, f, 0.16666666666666666);
  p = fma(p, f, 0.5);
  p = fma(p, f, 1.0);
  p = fma(p, f, 1.0);
  return ldexp(p, (int)nd);
}

__device__ __forceinline__ double gumbel_pool9(const double (&acc)[9],
                                               double bb, uint64_t base,
                                               uint32_t kp0, uint32_t kp1) {
  double bestv = -1e308, bA = 1.0, bQ = 0.0;
#pragma unroll
  for (int k = 0; k < 9; ++k) {
    double pre = (acc[k] + bb) * INV_SIGMA2;
    double q = fast_exp(-fabs(pre));
    double A = pre >= 0.0 ? 1.0 : q;          // p = A/(1+q)
    double opq = 1.0 + q;
    double L = fast_log(fma(EPS_D, opq, A)) - fast_log(opq);
    uint32_t o0, o1;
    uint64_t idx = base + (uint64_t)k;
    threefry2x32(kp0, kp1, (uint32_t)(idx >> 32), (uint32_t)idx, &o0, &o1);
    uint32_t bits = o0 ^ o1;
    float u = __uint_as_float((bits >> 9) | 0x3f800000u) - 1.0f;
    if (u == 0.0f) u = 1.17549435e-38f;
    float lg1 = (float)fast_log((double)u);
    double lg2 = fast_log(-(double)lg1);
    float gf = -(float)lg2;
    double v = L + (double)gf;
    if (v > bestv) { bestv = v; bA = A; bQ = q; }   // first-occurrence argmax
  }
  return bA / (1.0 + bQ);
}

__device__ __forceinline__ double gumbel_pool9_gap(const double (&acc)[9],
                                                   double bb, uint64_t base,
                                                   uint32_t kp0, uint32_t kp1,
                                                   double* gap) {
  double bestv = -1e308, second = -1e308, bA = 1.0, bQ = 0.0;
#pragma unroll
  for (int k = 0; k < 9; ++k) {
    double pre = (acc[k] + bb) * INV_SIGMA2;
    double q = fast_exp(-fabs(pre));
    double A = pre >= 0.0 ? 1.0 : q;
    double opq = 1.0 + q;
    double L = fast_log(fma(EPS_D, opq, A)) - fast_log(opq);
    uint32_t o0, o1;
    uint64_t idx = base + (uint64_t)k;
    threefry2x32(kp0, kp1, (uint32_t)(idx >> 32), (uint32_t)idx, &o0, &o1);
    uint32_t bits = o0 ^ o1;
    float u = __uint_as_float((bits >> 9) | 0x3f800000u) - 1.0f;
    if (u == 0.0f) u = 1.17549435e-38f;
    float lg1 = (float)fast_log((double)u);
    double lg2 = fast_log(-(double)lg1);
    float gf = -(float)lg2;
    double v = L + (double)gf;
    if (v > bestv) { second = bestv; bestv = v; bA = A; bQ = q; }
    else if (v > second) second = v;
  }
  *gap = bestv - second;
  return bA / (1.0 + bQ);
}

// ---- f64 vertical output pair (l1 + fallback l2; R8-verified) ----
template <int LDSTRIDE, typename T>
__device__ __forceinline__ void conv_pair(const T* __restrict__ xb,
                                          const double (&w)[49],
                                          double (&a0)[9], double (&a1)[9]) {
#pragma unroll
  for (int pr = 0; pr < 12; ++pr) {
    double xr[9];
#pragma unroll
    for (int c = 0; c < 9; ++c) xr[c] = (double)xb[pr * LDSTRIDE + c];
#pragma unroll
    for (int ki = 0; ki < 3; ++ki) {
      const int u0 = pr - ki;
      if (u0 >= 0 && u0 <= 6) {
#pragma unroll
        for (int kj = 0; kj < 3; ++kj)
#pragma unroll
          for (int v = 0; v < 7; ++v)
            a0[ki * 3 + kj] = fma(xr[kj + v], w[u0 * 7 + v], a0[ki * 3 + kj]);
      }
      const int u1 = pr - 3 - ki;
      if (u1 >= 0 && u1 <= 6) {
#pragma unroll
        for (int kj = 0; kj < 3; ++kj)
#pragma unroll
          for (int v = 0; v < 7; ++v)
            a1[ki * 3 + kj] = fma(xr[kj + v], w[u1 * 7 + v], a1[ki * 3 + kj]);
      }
    }
  }
}

// ---- l2 horizontal-pair step: one patch row PR (0..8), outputs (bh, bwp0)
// and (bh, bwp0+1). 12 cols via 6 explicit float2 (ds_read_b64). Order per
// acc: PR asc -> u asc for fixed kh, v asc == reference order within chunk.
// Row stride 40: bank = 24bh+8PR+6c+2k mod 32 -> exact 2-way (free).
template <int PR>
__device__ __forceinline__ void hp_step40(const float* __restrict__ xb,
                                          const float (&w)[49],
                                          float (&c0)[9], float (&c1)[9]) {
  float xr[12];
  const float2* __restrict__ row = (const float2*)(xb + PR * 40);  // even base
#pragma unroll
  for (int k = 0; k < 6; ++k) { float2 v2 = row[k]; xr[2 * k] = v2.x; xr[2 * k + 1] = v2.y; }
#pragma unroll
  for (int kh = 0; kh < 3; ++kh) {
    const int u = PR - kh;
    if (u >= 0 && u <= 6) {
#pragma unroll
      for (int kw = 0; kw < 3; ++kw)
#pragma unroll
        for (int v = 0; v < 7; ++v) {
          c0[kh * 3 + kw] = fmaf(xr[kw + v],     w[u * 7 + v], c0[kh * 3 + kw]);
          c1[kh * 3 + kw] = fmaf(xr[3 + kw + v], w[u * 7 + v], c1[kh * 3 + kw]);
        }
    }
  }
}

// ---------------- Layer 1 (f64, R8-verified; f32 shadow + init fold) -------
__global__ __launch_bounds__(256, 3) void l1_kernel(
    const float* __restrict__ x, const float* __restrict__ W1,
    const float* __restrict__ b1, double* __restrict__ h1,
    float* __restrict__ h1f32, int write_f32, unsigned int* __restrict__ cnt,
    uint32_t kp0, uint32_t kp1) {
  const int oc   = blockIdx.x;   // 96
  const int b    = blockIdx.y;   // 64
  const int half = blockIdx.z;   // 2
  const int t = threadIdx.x;
  const int wave = t >> 6;

  if (cnt && oc == 0 && b == 0 && half == 0 && t == 0) *cnt = 0u;

  __shared__ float xs[54 * 96];   // 20,736 B

  const int p0 = 14 * half;
  const bool active = t < 240;
  const int q = t / 30, bw = t - q * 30;
  const float* xb = xs + (6 * q) * 96 + 3 * bw;

  double a0[9] = {}, a1[9] = {};
  double w[49];

#pragma unroll 1
  for (int ic = 0; ic < 3; ++ic) {
    __syncthreads();
    {
      const char* gsrc = (const char*)(x + ((size_t)b * 3 + ic) * 9216 + (3 * p0) * 96);
#pragma unroll
      for (int p = 0; p < 6; ++p) {
        int elt = p * 256 + t;
        if (elt < 1296) {
          __builtin_amdgcn_global_load_lds(
              (const __attribute__((address_space(1))) void*)(gsrc + (size_t)elt * 16),
              (__attribute__((address_space(3))) void*)((char*)xs +
                                                        (size_t)(p * 256 + wave * 64) * 16),
              16, 0, 0);
        }
      }
    }
    __syncthreads();
    {
      const float* __restrict__ wsrc = W1 + (oc * 3 + ic) * 49;
#pragma unroll
      for (int j = 0; j < 49; ++j) w[j] = (double)wsrc[j];
    }
    if (active) conv_pair<96, float>(xb, w, a0, a1);
  }

  if (active) {
    const double bb = (double)b1[oc];
    const int bh0 = p0 + 2 * q;
#pragma unroll
    for (int j = 0; j < 2; ++j) {
      const int pos = (bh0 + j) * 30 + bw;
      const uint64_t base = ((uint64_t)((b * 96 + oc) * 900 + pos)) * 9ull;
      double pooled = gumbel_pool9(j ? a1 : a0, bb, base, kp0, kp1);
      const size_t oidx = (size_t)(b * 96 + oc) * 900 + pos;
      h1[oidx] = pooled;
      if (write_f32) h1f32[oidx] = (float)pooled;  // == cvt-on-read, bitwise
    }
  }
}

// ---------------- Layer 2 main: pure-f32 horizontal-pair, stride-40 LDS ----
// 256 thr = 8 oc (half-wave uniform) x 32 sp (8 bh x 4 col-pairs); thread
// computes outputs (bh, 2*(sp&3)) and (bh, 2*(sp&3)+1). Register-staged
// double buffer, 1-chunk-ahead prefetch, one barrier per chunk. c0/c1 f32
// accumulate across all 96 chunks (no f64 fold -- TAU redo covers ties);
// w[49] register-resident.
template <typename T>
__global__ __launch_bounds__(256, 2) void l2_kernel_hp(
    const T* __restrict__ hsrc, const float* __restrict__ W2,
    const float* __restrict__ b2, float* __restrict__ out,
    unsigned int* __restrict__ cnt, unsigned int* __restrict__ list,
    uint32_t kp0, uint32_t kp1) {
  const int octile = blockIdx.x;  // 24
  const int b      = blockIdx.y;  // 64
  const int t = threadIdx.x;      // 256
  const int oc_local = t >> 5;    // 0..7
  const int sp = t & 31;
  const int bh = sp >> 2;         // 0..7
  const int bwp0 = 2 * (sp & 3);  // 0,2,4,6
  const int oc = octile * 8 + oc_local;

  __shared__ float hs[2][30 * 40];   // 9,600 B (stride 40: float2 + 2-way banks)
  __shared__ float wsf[2][8 * 52];   // 3,328 B (w stride 52: float2-aligned)

  const T* __restrict__ hb = hsrc + (size_t)b * 86400;
  const float* __restrict__ wg = W2 + (size_t)octile * 8 * 4704;

  // staging slots (coverage: 4*256=1024>=900, 2*256=512>=392 -- AUDITED)
  int hj[4], hladdr[4]; bool hv[4];
#pragma unroll
  for (int p = 0; p < 4; ++p) {
    int j = p * 256 + t;
    hv[p] = j < 900; hj[p] = hv[p] ? j : 0;
    int r = hj[p] / 30, cc = hj[p] - r * 30;
    hladdr[p] = r * 40 + cc;
  }
  int wj[2], wladdr[2]; size_t wgoff[2]; bool wv[2];
#pragma unroll
  for (int p = 0; p < 2; ++p) {
    int j = p * 256 + t;
    wv[p] = j < 392; wj[p] = wv[p] ? j : 0;
    int oi = wj[p] / 49, rem = wj[p] - oi * 49;
    wgoff[p] = (size_t)oi * 4704 + rem;
    wladdr[p] = oi * 52 + rem;
  }

  float hr[4], wr[2];
#pragma unroll
  for (int p = 0; p < 4; ++p) if (hv[p]) hr[p] = (float)hb[hj[p]];
#pragma unroll
  for (int p = 0; p < 2; ++p) if (wv[p]) wr[p] = wg[wgoff[p]];
#pragma unroll
  for (int p = 0; p < 4; ++p) if (hv[p]) hs[0][hladdr[p]] = hr[p];
#pragma unroll
  for (int p = 0; p < 2; ++p) if (wv[p]) wsf[0][wladdr[p]] = wr[p];
#pragma unroll
  for (int p = 0; p < 4; ++p) if (hv[p]) hr[p] = (float)hb[900 + hj[p]];
#pragma unroll
  for (int p = 0; p < 2; ++p) if (wv[p]) wr[p] = wg[wgoff[p] + 49];

  float c0[9] = {}, c1[9] = {};   // pure f32 accumulators, all 96 ics
  float w[49];
  const float* xbase0 = &hs[0][(3 * bh) * 40 + 3 * bwp0];  // 120bh+6(sp&3): even
  const float* xbase1 = &hs[1][(3 * bh) * 40 + 3 * bwp0];

#pragma unroll 1
  for (int c = 0; c < 96; ++c) {
    __syncthreads();   // buf c&1 complete; readers of buf (c+1)&1 done
    if (c + 1 < 96) {
      const int nb = (c + 1) & 1;
#pragma unroll
      for (int p = 0; p < 4; ++p) if (hv[p]) hs[nb][hladdr[p]] = hr[p];
#pragma unroll
      for (int p = 0; p < 2; ++p) if (wv[p]) wsf[nb][wladdr[p]] = wr[p];
      if (c + 2 < 96) {
#pragma unroll
        for (int p = 0; p < 4; ++p)
          if (hv[p]) hr[p] = (float)hb[(size_t)(c + 2) * 900 + hj[p]];
#pragma unroll
        for (int p = 0; p < 2; ++p)
          if (wv[p]) wr[p] = wg[wgoff[p] + (size_t)(c + 2) * 49];
      }
    }
    {
      const float* __restrict__ wsrc = &wsf[c & 1][oc_local * 52];  // even base
      const float2* __restrict__ wp2 = (const float2*)wsrc;
#pragma unroll
      for (int k = 0; k < 24; ++k) { float2 v2 = wp2[k]; w[2 * k] = v2.x; w[2 * k + 1] = v2.y; }
      w[48] = wsrc[48];
      const float* xb = (c & 1) ? xbase1 : xbase0;
      hp_step40<0>(xb, w, c0, c1);
      hp_step40<1>(xb, w, c0, c1);
      hp_step40<2>(xb, w, c0, c1);
      hp_step40<3>(xb, w, c0, c1);
      hp_step40<4>(xb, w, c0, c1);
      hp_step40<5>(xb, w, c0, c1);
      hp_step40<6>(xb, w, c0, c1);
      hp_step40<7>(xb, w, c0, c1);
      hp_step40<8>(xb, w, c0, c1);
    }
  }

  double a0[9], a1[9];
#pragma unroll
  for (int k = 0; k < 9; ++k) { a0[k] = (double)c0[k]; a1[k] = (double)c1[k]; }

  const double bb = (double)b2[oc];
#pragma unroll
  for (int j = 0; j < 2; ++j) {
    const int bwp = bwp0 + j;
    const unsigned int oid = (unsigned int)((b * 192 + oc) * 64 + bh * 8 + bwp);
    const uint64_t base = (uint64_t)oid * 9ull;
    double gap;
    double pooled = gumbel_pool9_gap(j ? a1 : a0, bb, base, kp0, kp1, &gap);
    out[oid] = (float)pooled;
    if (gap < TAU) {
      unsigned int idx = atomicAdd(cnt, 1u);
      if (idx < REDO_CAP) list[idx] = oid;
    }
  }
}

// ---------------- Layer 2 fallback (pure f64, R8/R12-verified) -------------
__global__ __launch_bounds__(256, 3) void l2_kernel_f64(
    const double* __restrict__ h1, const float* __restrict__ W2,
    const float* __restrict__ b2, float* __restrict__ out,
    uint32_t kp0, uint32_t kp1) {
  const int octile = blockIdx.x;
  const int b      = blockIdx.y;
  const int t = threadIdx.x;
  const int wave = t >> 6;
  const int oc_local = t >> 5;
  const int li = t & 31;
  const int bw = li & 7;
  const int ph = 2 * ((li >> 3) & 1) + (li >> 4);
  const int bh0 = 2 * ph;
  const int oc = octile * 8 + oc_local;

  __shared__ double hs[2][900];
  __shared__ double wsd[2][392];

  const double* __restrict__ hb = h1 + (size_t)b * 86400;
  const float* __restrict__ wg = W2 + (size_t)octile * 8 * 4704;

  double a0[9] = {}, a1[9] = {};
  double w[49];

  auto stage = [&](int c, int buf) {
    const char* gsrc = (const char*)(hb + (size_t)c * 900);
#pragma unroll
    for (int p = 0; p < 2; ++p) {
      int elt = p * 256 + t;
      if (elt < 450) {
        __builtin_amdgcn_global_load_lds(
            (const __attribute__((address_space(1))) void*)(gsrc + (size_t)elt * 16),
            (__attribute__((address_space(3))) void*)((char*)&hs[buf][0] +
                                                      (size_t)(p * 256 + wave * 64) * 16),
            16, 0, 0);
      }
    }
#pragma unroll
    for (int p = 0; p < 2; ++p) {   // TWO passes (392 > 256)
      int j = p * 256 + t;
      if (j < 392) {
        int oi = j / 49, rem = j - oi * 49;
        wsd[buf][j] = (double)wg[(size_t)oi * 4704 + c * 49 + rem];
      }
    }
  };

  stage(0, 0);
#pragma unroll 1
  for (int c = 0; c < 96; ++c) {
    __syncthreads();
    if (c + 1 < 96) stage(c + 1, (c + 1) & 1);
    {
      const double* __restrict__ wsrc = &wsd[c & 1][oc_local * 49];
#pragma unroll
      for (int j = 0; j < 49; ++j) w[j] = wsrc[j];
      const double* xb = &hs[c & 1][(6 * ph) * 30 + 3 * bw];
      conv_pair<30, double>(xb, w, a0, a1);
    }
  }

  const double bb = (double)b2[oc];
#pragma unroll
  for (int j = 0; j < 2; ++j) {
    const int bh = bh0 + j;
    const uint64_t base = ((uint64_t)(((b * 192 + oc) * 8 + bh) * 8 + bw)) * 9ull;
    double pooled = gumbel_pool9(j ? a1 : a0, bb, base, kp0, kp1);
    out[(size_t)(b * 192 + oc) * 64 + bh * 8 + bw] = (float)pooled;
  }
}

// ---------------- Layer 2 tie-redo (exact f64 from h1_f64) ----------------
__global__ __launch_bounds__(64) void l2_redo_kernel(
    const double* __restrict__ h1, const float* __restrict__ W2,
    const float* __restrict__ b2, float* __restrict__ out,
    const unsigned int* __restrict__ cnt, const unsigned int* __restrict__ list,
    uint32_t kp0, uint32_t kp1) {
  unsigned int n = *cnt;
  if (n > REDO_CAP) n = REDO_CAP;
  if (blockIdx.x >= n) return;
  const unsigned int oid = list[blockIdx.x];
  const int sp = oid & 63, bh = sp >> 3, bw = sp & 7;
  const int rest = oid >> 6, oc = rest % 192, b = rest / 192;
  const int lane = threadIdx.x;

  double acc[9] = {};
  for (int ic = lane; ic < 96; ic += 64) {
    const double* __restrict__ xp =
        h1 + ((size_t)(b * 96 + ic) * 30 + 3 * bh) * 30 + 3 * bw;
    const float* __restrict__ wp = W2 + ((size_t)oc * 96 + ic) * 49;
    double w[49];
#pragma unroll
    for (int j = 0; j < 49; ++j) w[j] = (double)wp[j];
#pragma unroll
    for (int pr = 0; pr < 9; ++pr) {
      double xr[9];
#pragma unroll
      for (int c = 0; c < 9; ++c) xr[c] = xp[pr * 30 + c];
#pragma unroll
      for (int kh = 0; kh < 3; ++kh) {
        const int u = pr - kh;
        if (u >= 0 && u <= 6) {
#pragma unroll
          for (int kw = 0; kw < 3; ++kw)
#pragma unroll
            for (int v = 0; v < 7; ++v)
              acc[kh * 3 + kw] = fma(xr[kw + v], w[u * 7 + v], acc[kh * 3 + kw]);
        }
      }
    }
  }
#pragma unroll
  for (int off = 32; off; off >>= 1)
#pragma unroll
    for (int k = 0; k < 9; ++k) acc[k] += __shfl_down(acc[k], off);

  if (lane == 0) {
    const uint64_t base = (uint64_t)oid * 9ull;
    double pooled = gumbel_pool9(acc, (double)b2[oc], base, kp0, kp1);
    out[oid] = (float)pooled;
  }
}

extern "C" void kernel_launch(void* const* d_in, const int* in_sizes, int n_in,
                              void* d_out, int out_size, void* d_ws,
                              size_t ws_size, hipStream_t stream) {
  const float* x  = (const float*)d_in[0];   // [64,3,96,96]
  const float* W1 = (const float*)d_in[1];   // [96,3,7,7]
  const float* b1 = (const float*)d_in[2];   // [96]
  const float* W2 = (const float*)d_in[3];   // [192,96,7,7]
  const float* b2 = (const float*)d_in[4];   // [192]
  float* out = (float*)d_out;                // [64,192,8,8]
  double* h1   = (double*)d_ws;              // 44.24 MB f64
  float* h1f32 = (float*)((char*)d_ws + H1_BYTES);  // 22.12 MB f32 (full tier)

  uint32_t kp1a, kp1b, kp2a, kp2b;
  threefry2x32(0u, 42u, 0u, 0u, &kp1a, &kp1b);
  threefry2x32(0u, 42u, 0u, 1u, &kp2a, &kp2b);

  const size_t need_full = H1_BYTES + H1F32_BYTES + 16 + (size_t)REDO_CAP * 4;
  const size_t need_mid  = H1_BYTES + 16 + (size_t)REDO_CAP * 4;

  if (ws_size >= need_full) {          // launch-constant branches: graph-safe
    unsigned int* cnt  = (unsigned int*)((char*)d_ws + H1_BYTES + H1F32_BYTES);
    unsigned int* list = cnt + 4;
    l1_kernel<<<dim3(96, 64, 2), 256, 0, stream>>>(x, W1, b1, h1, h1f32, 1,
                                                   cnt, kp1a, kp1b);
    l2_kernel_hp<float><<<dim3(24, 64), 256, 0, stream>>>(
        h1f32, W2, b2, out, cnt, list, kp2a, kp2b);
    l2_redo_kernel<<<REDO_CAP, 64, 0, stream>>>(h1, W2, b2, out, cnt, list,
                                                kp2a, kp2b);
  } else if (ws_size >= need_mid) {
    unsigned int* cnt  = (unsigned int*)((char*)d_ws + H1_BYTES);
    unsigned int* list = cnt + 4;
    l1_kernel<<<dim3(96, 64, 2), 256, 0, stream>>>(x, W1, b1, h1, h1f32, 0,
                                                   cnt, kp1a, kp1b);
    l2_kernel_hp<double><<<dim3(24, 64), 256, 0, stream>>>(
        h1, W2, b2, out, cnt, list, kp2a, kp2b);
    l2_redo_kernel<<<REDO_CAP, 64, 0, stream>>>(h1, W2, b2, out, cnt, list,
                                                kp2a, kp2b);
  } else {
    l1_kernel<<<dim3(96, 64, 2), 256, 0, stream>>>(x, W1, b1, h1, h1f32, 0,
                                                   (unsigned int*)0, kp1a, kp1b);
    l2_kernel_f64<<<dim3(24, 64), 256, 0, stream>>>(h1, W2, b2, out,
                                                    kp2a, kp2b);
  }
}

// Round 2
// 1270.059 us; speedup vs baseline: 1.4334x; 1.4334x over previous
//
#include <hip/hip_runtime.h>
#include <cstdint>
#include <math.h>

// ConvDBN R16: l2 conv moved to MFMA (bf16x3 split, 6 products = f32-grade).
// R15 post-mortem: bank conflicts fell 2.5x, dur flat -> VALU-ISSUE-bound on
// 3.33e10 f32 FMAs (floor ~650us at 103 TF m07 ceiling). Only lever: matrix
// cores. l2 = tap-decomposed GEMM (K=ic), M-tile 192, N-tile 64, 4 waves
// 2Mx2N, Mf6xNf2 of 16x16x32 (m89-VERIFIED layouts: A row=l&15 k=(l>>4)*8+j;
// B col=l&15 same k; C col=l&15 row=(l>>4)*4+reg). A: LDS 3 split planes
// [g][row][x][8ic] (16B lane stride -> 2-way banks, free). B: W2 pre-split
// [tap][oc][ic] bf16 global, direct dwordx4 frag loads + 1-tap reg prefetch
// (keeps B off the LDS pipe; ~28 B/cyc/CU of L2, budget 133). Pool decoupled:
// conv f32 [b][m][oc] -> pool kernel (same RNG oid*9+k, TAU flags, redo).
// Numerics: 6-product bf16x3 kept-term err ~2^-24|hw|; f32-acc rounding
// ~1e-5 == current f32 chain -> TAU=6e-3 scheme unchanged. h1 f64 DROPPED:
// redo exact-f64 from h1f32 (matches f32-input reference semantics; dPre
// ~1e-6 << TAU). ws = 22.1(h1f32) + 28.3(conv) + 5.4(w2 splits) + cnt/list
// = 56.0 MB < 66.5 MB proven available. l1 untouched.

#define EPS_D 1e-8
#define INV_SIGMA2 (1.0 / (0.2 * 0.2))
#define TAU 6e-3
#define REDO_CAP 32768
#define H1_BYTES (5529600ull * 8ull)
#define H1F32_BYTES (5529600ull * 4ull)
#define CONV_BYTES (64ull * 576ull * 192ull * 4ull)
#define WSPLIT_ELEMS (49ull * 192ull * 96ull)

typedef __bf16 bf16x8 __attribute__((ext_vector_type(8)));
typedef float f32x4 __attribute__((ext_vector_type(4)));

#define MFMA(A_, B_, C_) \
  __builtin_amdgcn_mfma_f32_16x16x32_bf16((A_), (B_), (C_), 0, 0, 0)

__host__ __device__ __forceinline__ void threefry2x32(
    uint32_t k0, uint32_t k1, uint32_t x0, uint32_t x1,
    uint32_t* o0, uint32_t* o1) {
  const uint32_t ks0 = k0, ks1 = k1, ks2 = k0 ^ k1 ^ 0x1BD11BDAu;
  x0 += ks0; x1 += ks1;
#define TF_R(r) { x0 += x1; x1 = (x1 << (r)) | (x1 >> (32 - (r))); x1 ^= x0; }
  TF_R(13) TF_R(15) TF_R(26) TF_R(6)
  x0 += ks1; x1 += ks2 + 1u;
  TF_R(17) TF_R(29) TF_R(16) TF_R(24)
  x0 += ks2; x1 += ks0 + 2u;
  TF_R(13) TF_R(15) TF_R(26) TF_R(6)
  x0 += ks0; x1 += ks1 + 3u;
  TF_R(17) TF_R(29) TF_R(16) TF_R(24)
  x0 += ks1; x1 += ks2 + 4u;
  TF_R(13) TF_R(15) TF_R(26) TF_R(6)
  x0 += ks2; x1 += ks0 + 5u;
#undef TF_R
  *o0 = x0; *o1 = x1;
}

__device__ __forceinline__ double fast_log(double x) {
  long long ib = __double_as_longlong(x);
  int e = (int)((ib >> 52) & 0x7ff) - 1023;
  double r = __longlong_as_double((ib & 0xfffffffffffffLL) | 0x3ff0000000000000LL);
  if (r > 1.4142135623730951) { r *= 0.5; e += 1; }
  double s = (r - 1.0) / (r + 1.0);
  double s2 = s * s;
  double t = fma(s2, fma(s2, fma(s2, fma(s2, fma(s2, fma(s2,
      1.0/15.0, 1.0/13.0), 1.0/11.0), 1.0/9.0), 1.0/7.0), 1.0/5.0), 1.0/3.0);
  double lr = fma(2.0 * s * s2, t, 2.0 * s);
  return fma((double)e, 0.6931471805599453, lr);
}

__device__ __forceinline__ double fast_exp(double x) {
  double nd = rint(x * 1.4426950408889634);
  double f = fma(nd, -0.6931471803691238, x);
  f = fma(nd, -1.9082149292705877e-10, f);
  double p = 2.505210838544172e-8;
  p = fma(p, f, 2.755731922398589e-7);
  p = fma(p, f, 2.7557319223985893e-6);
  p = fma(p, f, 2.48015873015873e-5);
  p = fma(p, f, 1.984126984126984e-4);
  p = fma(p, f, 1.3888888888888889e-3);
  p = fma(p, f, 8.333333333333333e-3);
  p = fma(p, f, 4.1666666666666664e-2);
  p = fma(p, f, 0.16666666666666666);
  p = fma(p, f, 0.5);
  p = fma(p, f, 1.0);
  p = fma(p, f, 1.0);
  return ldexp(p, (int)nd);
}

__device__ __forceinline__ double gumbel_pool9(const double (&acc)[9],
                                               double bb, uint64_t base,
                                               uint32_t kp0, uint32_t kp1) {
  double bestv = -1e308, bA = 1.0, bQ = 0.0;
#pragma unroll
  for (int k = 0; k < 9; ++k) {
    double pre = (acc[k] + bb) * INV_SIGMA2;
    double q = fast_exp(-fabs(pre));
    double A = pre >= 0.0 ? 1.0 : q;          // p = A/(1+q)
    double opq = 1.0 + q;
    double L = fast_log(fma(EPS_D, opq, A)) - fast_log(opq);
    uint32_t o0, o1;
    uint64_t idx = base + (uint64_t)k;
    threefry2x32(kp0, kp1, (uint32_t)(idx >> 32), (uint32_t)idx, &o0, &o1);
    uint32_t bits = o0 ^ o1;
    float u = __uint_as_float((bits >> 9) | 0x3f800000u) - 1.0f;
    if (u == 0.0f) u = 1.17549435e-38f;
    float lg1 = (float)fast_log((double)u);
    double lg2 = fast_log(-(double)lg1);
    float gf = -(float)lg2;
    double v = L + (double)gf;
    if (v > bestv) { bestv = v; bA = A; bQ = q; }   // first-occurrence argmax
  }
  return bA / (1.0 + bQ);
}

__device__ __forceinline__ double gumbel_pool9_gap(const double (&acc)[9],
                                                   double bb, uint64_t base,
                                                   uint32_t kp0, uint32_t kp1,
                                                   double* gap) {
  double bestv = -1e308, second = -1e308, bA = 1.0, bQ = 0.0;
#pragma unroll
  for (int k = 0; k < 9; ++k) {
    double pre = (acc[k] + bb) * INV_SIGMA2;
    double q = fast_exp(-fabs(pre));
    double A = pre >= 0.0 ? 1.0 : q;
    double opq = 1.0 + q;
    double L = fast_log(fma(EPS_D, opq, A)) - fast_log(opq);
    uint32_t o0, o1;
    uint64_t idx = base + (uint64_t)k;
    threefry2x32(kp0, kp1, (uint32_t)(idx >> 32), (uint32_t)idx, &o0, &o1);
    uint32_t bits = o0 ^ o1;
    float u = __uint_as_float((bits >> 9) | 0x3f800000u) - 1.0f;
    if (u == 0.0f) u = 1.17549435e-38f;
    float lg1 = (float)fast_log((double)u);
    double lg2 = fast_log(-(double)lg1);
    float gf = -(float)lg2;
    double v = L + (double)gf;
    if (v > bestv) { second = bestv; bestv = v; bA = A; bQ = q; }
    else if (v > second) second = v;
  }
  *gap = bestv - second;
  return bA / (1.0 + bQ);
}

__device__ __forceinline__ unsigned short f32_to_bf16(float v) {
  uint32_t u = __float_as_uint(v);
  return (unsigned short)((u + 0x7fffu + ((u >> 16) & 1u)) >> 16);
}
__device__ __forceinline__ float bf16_to_f32(unsigned short s) {
  return __uint_as_float(((uint32_t)s) << 16);
}

// ---- f64 vertical output pair (l1 + fallback l2; R8-verified) ----
template <int LDSTRIDE, typename T>
__device__ __forceinline__ void conv_pair(const T* __restrict__ xb,
                                          const double (&w)[49],
                                          double (&a0)[9], double (&a1)[9]) {
#pragma unroll
  for (int pr = 0; pr < 12; ++pr) {
    double xr[9];
#pragma unroll
    for (int c = 0; c < 9; ++c) xr[c] = (double)xb[pr * LDSTRIDE + c];
#pragma unroll
    for (int ki = 0; ki < 3; ++ki) {
      const int u0 = pr - ki;
      if (u0 >= 0 && u0 <= 6) {
#pragma unroll
        for (int kj = 0; kj < 3; ++kj)
#pragma unroll
          for (int v = 0; v < 7; ++v)
            a0[ki * 3 + kj] = fma(xr[kj + v], w[u0 * 7 + v], a0[ki * 3 + kj]);
      }
      const int u1 = pr - 3 - ki;
      if (u1 >= 0 && u1 <= 6) {
#pragma unroll
        for (int kj = 0; kj < 3; ++kj)
#pragma unroll
          for (int v = 0; v < 7; ++v)
            a1[ki * 3 + kj] = fma(xr[kj + v], w[u1 * 7 + v], a1[ki * 3 + kj]);
      }
    }
  }
}

// ---- l2 fallback hp step (R15, stride-40) ----
template <int PR>
__device__ __forceinline__ void hp_step40(const float* __restrict__ xb,
                                          const float (&w)[49],
                                          float (&c0)[9], float (&c1)[9]) {
  float xr[12];
  const float2* __restrict__ row = (const float2*)(xb + PR * 40);
#pragma unroll
  for (int k = 0; k < 6; ++k) { float2 v2 = row[k]; xr[2 * k] = v2.x; xr[2 * k + 1] = v2.y; }
#pragma unroll
  for (int kh = 0; kh < 3; ++kh) {
    const int u = PR - kh;
    if (u >= 0 && u <= 6) {
#pragma unroll
      for (int kw = 0; kw < 3; ++kw)
#pragma unroll
        for (int v = 0; v < 7; ++v) {
          c0[kh * 3 + kw] = fmaf(xr[kw + v],     w[u * 7 + v], c0[kh * 3 + kw]);
          c1[kh * 3 + kw] = fmaf(xr[3 + kw + v], w[u * 7 + v], c1[kh * 3 + kw]);
        }
    }
  }
}

// ---------------- Layer 1 (f64, R8-verified; dual-write flags) -------------
__global__ __launch_bounds__(256, 3) void l1_kernel(
    const float* __restrict__ x, const float* __restrict__ W1,
    const float* __restrict__ b1, double* __restrict__ h1,
    float* __restrict__ h1f32, int write_f64, int write_f32,
    unsigned int* __restrict__ cnt, uint32_t kp0, uint32_t kp1) {
  const int oc   = blockIdx.x;   // 96
  const int b    = blockIdx.y;   // 64
  const int half = blockIdx.z;   // 2
  const int t = threadIdx.x;
  const int wave = t >> 6;

  if (cnt && oc == 0 && b == 0 && half == 0 && t == 0) *cnt = 0u;

  __shared__ float xs[54 * 96];   // 20,736 B

  const int p0 = 14 * half;
  const bool active = t < 240;
  const int q = t / 30, bw = t - q * 30;
  const float* xb = xs + (6 * q) * 96 + 3 * bw;

  double a0[9] = {}, a1[9] = {};
  double w[49];

#pragma unroll 1
  for (int ic = 0; ic < 3; ++ic) {
    __syncthreads();
    {
      const char* gsrc = (const char*)(x + ((size_t)b * 3 + ic) * 9216 + (3 * p0) * 96);
#pragma unroll
      for (int p = 0; p < 6; ++p) {
        int elt = p * 256 + t;
        if (elt < 1296) {
          __builtin_amdgcn_global_load_lds(
              (const __attribute__((address_space(1))) void*)(gsrc + (size_t)elt * 16),
              (__attribute__((address_space(3))) void*)((char*)xs +
                                                        (size_t)(p * 256 + wave * 64) * 16),
              16, 0, 0);
        }
      }
    }
    __syncthreads();
    {
      const float* __restrict__ wsrc = W1 + (oc * 3 + ic) * 49;
#pragma unroll
      for (int j = 0; j < 49; ++j) w[j] = (double)wsrc[j];
    }
    if (active) conv_pair<96, float>(xb, w, a0, a1);
  }

  if (active) {
    const double bb = (double)b1[oc];
    const int bh0 = p0 + 2 * q;
#pragma unroll
    for (int j = 0; j < 2; ++j) {
      const int pos = (bh0 + j) * 30 + bw;
      const uint64_t base = ((uint64_t)((b * 96 + oc) * 900 + pos)) * 9ull;
      double pooled = gumbel_pool9(j ? a1 : a0, bb, base, kp0, kp1);
      const size_t oidx = (size_t)(b * 96 + oc) * 900 + pos;
      if (write_f64) h1[oidx] = pooled;
      if (write_f32) h1f32[oidx] = (float)pooled;
    }
  }
}

// ---------------- W2 bf16x3 split: [oc][ic][tap] f32 -> [tap][oc][ic] ------
__global__ __launch_bounds__(256) void w2_split_kernel(
    const float* __restrict__ W2, unsigned short* __restrict__ s0,
    unsigned short* __restrict__ s1, unsigned short* __restrict__ s2) {
  int idx = blockIdx.x * 256 + threadIdx.x;      // 903168 = 3528*256 exact
  int ic = idx % 96; int rest = idx / 96;
  int oc = rest % 192; int tap = rest / 192;
  float v = W2[(size_t)(oc * 96 + ic) * 49 + tap];
  unsigned short a = f32_to_bf16(v); float r1 = v - bf16_to_f32(a);
  unsigned short b = f32_to_bf16(r1); float r2 = r1 - bf16_to_f32(b);
  unsigned short c = f32_to_bf16(r2);
  s0[idx] = a; s1[idx] = b; s2[idx] = c;
}

// ---------------- Layer 2 conv via MFMA (bf16x3, 6 products) ---------------
// Block: M-tile 192 (raster m within one b, mt in 0..2), N-tile 64.
// 4 waves 2Mx2N; wave = Mf6 x Nf2 frags of 16x16x32. A staged in LDS as
// 3 split planes [g(4)][row(14)][x(30)][j(8)] (granule-major: lane stride
// 16B -> 2-way banks, free). B direct from global w-split [tap][oc][ic],
// dwordx4 per frag, 1-tap register prefetch. Barriers only at ic-chunk
// boundaries (3 per block). C written to conv [b][m][oc] (oc-contig).
__global__ __launch_bounds__(256, 1) void l2_mfma_kernel(
    const float* __restrict__ h1f32, const unsigned short* __restrict__ wp0,
    const unsigned short* __restrict__ wp1,
    const unsigned short* __restrict__ wp2, float* __restrict__ conv) {
  const int nt = blockIdx.x;            // 0..2  (N-tile: 64 oc)
  const int my = blockIdx.y;            // 0..191 = b*3 + mt
  const int b = my / 3, mt = my - 3 * b;
  const int t = threadIdx.x;
  const int l = t & 63;
  const int w = t >> 6;
  const int wm = w >> 1, wn = w & 1;
  const int g = l >> 4;                 // 0..3 (k-granule)
  const int lr = l & 15;                // A-row / B-col lane index

  __shared__ unsigned short As[3 * 4 * 14 * 30 * 8];   // 80,640 B

  // per-lane A-row addressing: m_local = wm*96 + mf*16 + lr -> (yl,x)
  int rowoff[6];
#pragma unroll
  for (int mf = 0; mf < 6; ++mf) {
    int ml = wm * 96 + mf * 16 + lr;    // 0..191
    int yl = ml / 24, xx = ml - 24 * yl;
    rowoff[mf] = g * 3360 + (yl * 30 + xx) * 8;
  }
  const int oc0 = nt * 64 + wn * 32 + lr;

  f32x4 acc[6][2];
#pragma unroll
  for (int mf = 0; mf < 6; ++mf)
#pragma unroll
    for (int nf = 0; nf < 2; ++nf) acc[mf][nf] = (f32x4){0.f, 0.f, 0.f, 0.f};

#pragma unroll 1
  for (int ch = 0; ch < 3; ++ch) {
    __syncthreads();   // prior chunk's readers done
    {
      // stage h rows [8mt, 8mt+14) x 30 cols x 32 ics, split to 3 bf16 planes
      const float* __restrict__ hb =
          h1f32 + ((size_t)b * 96 + ch * 32) * 900 + (8 * mt) * 30;
#pragma unroll 1
      for (int idx = t; idx < 13440; idx += 256) {
        int i = idx / 420, rem = idx - i * 420;   // i = ic-local, rem = r*30+x
        float v = hb[(size_t)i * 900 + rem];
        unsigned short p0 = f32_to_bf16(v);
        float r1 = v - bf16_to_f32(p0);
        unsigned short p1 = f32_to_bf16(r1);
        float r2 = r1 - bf16_to_f32(p1);
        unsigned short p2 = f32_to_bf16(r2);
        int base = (i >> 3) * 3360 + rem * 8 + (i & 7);
        As[base] = p0; As[base + 13440] = p1; As[base + 26880] = p2;
      }
    }
    __syncthreads();

    int boff = oc0 * 96 + ch * 32 + 8 * g;   // elem index; +18432/tap
    bf16x8 bc[2][3], bn[2][3];
#pragma unroll
    for (int nf = 0; nf < 2; ++nf) {
      bc[nf][0] = *(const bf16x8*)&wp0[boff + nf * 1536];
      bc[nf][1] = *(const bf16x8*)&wp1[boff + nf * 1536];
      bc[nf][2] = *(const bf16x8*)&wp2[boff + nf * 1536];
    }
    int kh = 0, kw = 0;
#pragma unroll 1
    for (int tap = 0; tap < 49; ++tap) {
      if (tap < 48) {
        const int bo2 = boff + 18432;
#pragma unroll
        for (int nf = 0; nf < 2; ++nf) {
          bn[nf][0] = *(const bf16x8*)&wp0[bo2 + nf * 1536];
          bn[nf][1] = *(const bf16x8*)&wp1[bo2 + nf * 1536];
          bn[nf][2] = *(const bf16x8*)&wp2[bo2 + nf * 1536];
        }
        boff = bo2;
      }
      const int tapoff = (kh * 30 + kw) * 8;
#pragma unroll
      for (int mf = 0; mf < 6; ++mf) {
        const int ab = rowoff[mf] + tapoff;
        bf16x8 a0 = *(const bf16x8*)&As[ab];
        bf16x8 a1 = *(const bf16x8*)&As[ab + 13440];
        bf16x8 a2 = *(const bf16x8*)&As[ab + 26880];
#pragma unroll
        for (int nf = 0; nf < 2; ++nf) {
          f32x4 c = acc[mf][nf];
          c = MFMA(a0, bc[nf][0], c);   // (0,0)
          c = MFMA(a0, bc[nf][1], c);   // (0,1)
          c = MFMA(a1, bc[nf][0], c);   // (1,0)
          c = MFMA(a1, bc[nf][1], c);   // (1,1)
          c = MFMA(a0, bc[nf][2], c);   // (0,2)
          c = MFMA(a2, bc[nf][0], c);   // (2,0)
          acc[mf][nf] = c;
        }
      }
      if (tap < 48) {
#pragma unroll
        for (int nf = 0; nf < 2; ++nf)
#pragma unroll
          for (int s = 0; s < 3; ++s) bc[nf][s] = bn[nf][s];
      }
      if (++kw == 7) { kw = 0; ++kh; }
    }
  }

  // C write: conv [b][m 576][oc 192]; C row = g*4 + reg, col = lr
  const int rowsub = g * 4;
#pragma unroll
  for (int mf = 0; mf < 6; ++mf)
#pragma unroll
    for (int nf = 0; nf < 2; ++nf)
#pragma unroll
      for (int r = 0; r < 4; ++r) {
        const int m_abs = mt * 192 + wm * 96 + mf * 16 + rowsub + r;
        const int oc = oc0 + nf * 16;
        conv[((size_t)b * 576 + m_abs) * 192 + oc] = acc[mf][nf][r];
      }
}

// ---------------- Layer 2 pool (gumbel + gap flags from conv buffer) -------
__global__ __launch_bounds__(192) void l2_pool_kernel(
    const float* __restrict__ conv, const float* __restrict__ b2,
    float* __restrict__ out, unsigned int* __restrict__ cnt,
    unsigned int* __restrict__ list, uint32_t kp0, uint32_t kp1) {
  const int pos = blockIdx.x;   // 0..63 = ph*8+pw
  const int b = blockIdx.y;     // 64
  const int oc = threadIdx.x;   // 192
  const int ph = pos >> 3, pw = pos & 7;
  double a[9];
  const float* __restrict__ cb = conv + (size_t)b * 576 * 192 + oc;
#pragma unroll
  for (int dy = 0; dy < 3; ++dy)
#pragma unroll
    for (int dx = 0; dx < 3; ++dx)
      a[dy * 3 + dx] = (double)cb[((size_t)((3 * ph + dy) * 24 + 3 * pw + dx)) * 192];
  const unsigned int oid = (unsigned int)((b * 192 + oc) * 64 + pos);
  double gap;
  double pooled = gumbel_pool9_gap(a, (double)b2[oc], (uint64_t)oid * 9ull,
                                   kp0, kp1, &gap);
  out[oid] = (float)pooled;
  if (gap < TAU) {
    unsigned int idx = atomicAdd(cnt, 1u);
    if (idx < REDO_CAP) list[idx] = oid;
  }
}

// ---------------- Layer 2 fallback hp (R15 f32 path, kept as safety tier) --
template <typename T>
__global__ __launch_bounds__(256, 2) void l2_kernel_hp(
    const T* __restrict__ hsrc, const float* __restrict__ W2,
    const float* __restrict__ b2, float* __restrict__ out,
    unsigned int* __restrict__ cnt, unsigned int* __restrict__ list,
    uint32_t kp0, uint32_t kp1) {
  const int octile = blockIdx.x;
  const int b      = blockIdx.y;
  const int t = threadIdx.x;
  const int oc_local = t >> 5;
  const int sp = t & 31;
  const int bh = sp >> 2;
  const int bwp0 = 2 * (sp & 3);
  const int oc = octile * 8 + oc_local;

  __shared__ float hs[2][30 * 40];
  __shared__ float wsf[2][8 * 52];

  const T* __restrict__ hb = hsrc + (size_t)b * 86400;
  const float* __restrict__ wg = W2 + (size_t)octile * 8 * 4704;

  int hj[4], hladdr[4]; bool hv[4];
#pragma unroll
  for (int p = 0; p < 4; ++p) {
    int j = p * 256 + t;
    hv[p] = j < 900; hj[p] = hv[p] ? j : 0;
    int r = hj[p] / 30, cc = hj[p] - r * 30;
    hladdr[p] = r * 40 + cc;
  }
  int wj[2], wladdr[2]; size_t wgoff[2]; bool wv[2];
#pragma unroll
  for (int p = 0; p < 2; ++p) {
    int j = p * 256 + t;
    wv[p] = j < 392; wj[p] = wv[p] ? j : 0;
    int oi = wj[p] / 49, rem = wj[p] - oi * 49;
    wgoff[p] = (size_t)oi * 4704 + rem;
    wladdr[p] = oi * 52 + rem;
  }

  float hr[4], wr[2];
#pragma unroll
  for (int p = 0; p < 4; ++p) if (hv[p]) hr[p] = (float)hb[hj[p]];
#pragma unroll
  for (int p = 0; p < 2; ++p) if (wv[p]) wr[p] = wg[wgoff[p]];
#pragma unroll
  for (int p = 0; p < 4; ++p) if (hv[p]) hs[0][hladdr[p]] = hr[p];
#pragma unroll
  for (int p = 0; p < 2; ++p) if (wv[p]) wsf[0][wladdr[p]] = wr[p];
#pragma unroll
  for (int p = 0; p < 4; ++p) if (hv[p]) hr[p] = (float)hb[900 + hj[p]];
#pragma unroll
  for (int p = 0; p < 2; ++p) if (wv[p]) wr[p] = wg[wgoff[p] + 49];

  float c0[9] = {}, c1[9] = {};
  float w[49];
  const float* xbase0 = &hs[0][(3 * bh) * 40 + 3 * bwp0];
  const float* xbase1 = &hs[1][(3 * bh) * 40 + 3 * bwp0];

#pragma unroll 1
  for (int c = 0; c < 96; ++c) {
    __syncthreads();
    if (c + 1 < 96) {
      const int nb = (c + 1) & 1;
#pragma unroll
      for (int p = 0; p < 4; ++p) if (hv[p]) hs[nb][hladdr[p]] = hr[p];
#pragma unroll
      for (int p = 0; p < 2; ++p) if (wv[p]) wsf[nb][wladdr[p]] = wr[p];
      if (c + 2 < 96) {
#pragma unroll
        for (int p = 0; p < 4; ++p)
          if (hv[p]) hr[p] = (float)hb[(size_t)(c + 2) * 900 + hj[p]];
#pragma unroll
        for (int p = 0; p < 2; ++p)
          if (wv[p]) wr[p] = wg[wgoff[p] + (size_t)(c + 2) * 49];
      }
    }
    {
      const float* __restrict__ wsrc = &wsf[c & 1][oc_local * 52];
      const float2* __restrict__ wp2 = (const float2*)wsrc;
#pragma unroll
      for (int k = 0; k < 24; ++k) { float2 v2 = wp2[k]; w[2 * k] = v2.x; w[2 * k + 1] = v2.y; }
      w[48] = wsrc[48];
      const float* xb = (c & 1) ? xbase1 : xbase0;
      hp_step40<0>(xb, w, c0, c1);
      hp_step40<1>(xb, w, c0, c1);
      hp_step40<2>(xb, w, c0, c1);
      hp_step40<3>(xb, w, c0, c1);
      hp_step40<4>(xb, w, c0, c1);
      hp_step40<5>(xb, w, c0, c1);
      hp_step40<6>(xb, w, c0, c1);
      hp_step40<7>(xb, w, c0, c1);
      hp_step40<8>(xb, w, c0, c1);
    }
  }

  double a0[9], a1[9];
#pragma unroll
  for (int k = 0; k < 9; ++k) { a0[k] = (double)c0[k]; a1[k] = (double)c1[k]; }

  const double bb = (double)b2[oc];
#pragma unroll
  for (int j = 0; j < 2; ++j) {
    const int bwp = bwp0 + j;
    const unsigned int oid = (unsigned int)((b * 192 + oc) * 64 + bh * 8 + bwp);
    const uint64_t base = (uint64_t)oid * 9ull;
    double gap;
    double pooled = gumbel_pool9_gap(j ? a1 : a0, bb, base, kp0, kp1, &gap);
    out[oid] = (float)pooled;
    if (gap < TAU) {
      unsigned int idx = atomicAdd(cnt, 1u);
      if (idx < REDO_CAP) list[idx] = oid;
    }
  }
}

// ---------------- Layer 2 fallback (pure f64, R8-verified) -----------------
__global__ __launch_bounds__(256, 3) void l2_kernel_f64(
    const double* __restrict__ h1, const float* __restrict__ W2,
    const float* __restrict__ b2, float* __restrict__ out,
    uint32_t kp0, uint32_t kp1) {
  const int octile = blockIdx.x;
  const int b      = blockIdx.y;
  const int t = threadIdx.x;
  const int wave = t >> 6;
  const int oc_local = t >> 5;
  const int li = t & 31;
  const int bw = li & 7;
  const int ph = 2 * ((li >> 3) & 1) + (li >> 4);
  const int bh0 = 2 * ph;
  const int oc = octile * 8 + oc_local;

  __shared__ double hs[2][900];
  __shared__ double wsd[2][392];

  const double* __restrict__ hb = h1 + (size_t)b * 86400;
  const float* __restrict__ wg = W2 + (size_t)octile * 8 * 4704;

  double a0[9] = {}, a1[9] = {};
  double w[49];

  auto stage = [&](int c, int buf) {
    const char* gsrc = (const char*)(hb + (size_t)c * 900);
#pragma unroll
    for (int p = 0; p < 2; ++p) {
      int elt = p * 256 + t;
      if (elt < 450) {
        __builtin_amdgcn_global_load_lds(
            (const __attribute__((address_space(1))) void*)(gsrc + (size_t)elt * 16),
            (__attribute__((address_space(3))) void*)((char*)&hs[buf][0] +
                                                      (size_t)(p * 256 + wave * 64) * 16),
            16, 0, 0);
      }
    }
#pragma unroll
    for (int p = 0; p < 2; ++p) {
      int j = p * 256 + t;
      if (j < 392) {
        int oi = j / 49, rem = j - oi * 49;
        wsd[buf][j] = (double)wg[(size_t)oi * 4704 + c * 49 + rem];
      }
    }
  };

  stage(0, 0);
#pragma unroll 1
  for (int c = 0; c < 96; ++c) {
    __syncthreads();
    if (c + 1 < 96) stage(c + 1, (c + 1) & 1);
    {
      const double* __restrict__ wsrc = &wsd[c & 1][oc_local * 49];
#pragma unroll
      for (int j = 0; j < 49; ++j) w[j] = wsrc[j];
      const double* xb = &hs[c & 1][(6 * ph) * 30 + 3 * bw];
      conv_pair<30, double>(xb, w, a0, a1);
    }
  }

  const double bb = (double)b2[oc];
#pragma unroll
  for (int j = 0; j < 2; ++j) {
    const int bh = bh0 + j;
    const uint64_t base = ((uint64_t)(((b * 192 + oc) * 8 + bh) * 8 + bw)) * 9ull;
    double pooled = gumbel_pool9(j ? a1 : a0, bb, base, kp0, kp1);
    out[(size_t)(b * 192 + oc) * 64 + bh * 8 + bw] = (float)pooled;
  }
}

// ---------------- Layer 2 tie-redo (exact f64 from h1f32) ------------------
__global__ __launch_bounds__(64) void l2_redo_kernel(
    const float* __restrict__ h1f, const float* __restrict__ W2,
    const float* __restrict__ b2, float* __restrict__ out,
    const unsigned int* __restrict__ cnt, const unsigned int* __restrict__ list,
    uint32_t kp0, uint32_t kp1) {
  unsigned int n = *cnt;
  if (n > REDO_CAP) n = REDO_CAP;
  if (blockIdx.x >= n) return;
  const unsigned int oid = list[blockIdx.x];
  const int sp = oid & 63, bh = sp >> 3, bw = sp & 7;
  const int rest = oid >> 6, oc = rest % 192, b = rest / 192;
  const int lane = threadIdx.x;

  double acc[9] = {};
  for (int ic = lane; ic < 96; ic += 64) {
    const float* __restrict__ xp =
        h1f + ((size_t)(b * 96 + ic) * 30 + 3 * bh) * 30 + 3 * bw;
    const float* __restrict__ wp = W2 + ((size_t)oc * 96 + ic) * 49;
    double w[49];
#pragma unroll
    for (int j = 0; j < 49; ++j) w[j] = (double)wp[j];
#pragma unroll
    for (int pr = 0; pr < 9; ++pr) {
      double xr[9];
#pragma unroll
      for (int c = 0; c < 9; ++c) xr[c] = (double)xp[pr * 30 + c];
#pragma unroll
      for (int kh = 0; kh < 3; ++kh) {
        const int u = pr - kh;
        if (u >= 0 && u <= 6) {
#pragma unroll
          for (int kw = 0; kw < 3; ++kw)
#pragma unroll
            for (int v = 0; v < 7; ++v)
              acc[kh * 3 + kw] = fma(xr[kw + v], w[u * 7 + v], acc[kh * 3 + kw]);
        }
      }
    }
  }
#pragma unroll
  for (int off = 32; off; off >>= 1)
#pragma unroll
    for (int k = 0; k < 9; ++k) acc[k] += __shfl_down(acc[k], off);

  if (lane == 0) {
    const uint64_t base = (uint64_t)oid * 9ull;
    double pooled = gumbel_pool9(acc, (double)b2[oc], base, kp0, kp1);
    out[oid] = (float)pooled;
  }
}

extern "C" void kernel_launch(void* const* d_in, const int* in_sizes, int n_in,
                              void* d_out, int out_size, void* d_ws,
                              size_t ws_size, hipStream_t stream) {
  const float* x  = (const float*)d_in[0];   // [64,3,96,96]
  const float* W1 = (const float*)d_in[1];   // [96,3,7,7]
  const float* b1 = (const float*)d_in[2];   // [96]
  const float* W2 = (const float*)d_in[3];   // [192,96,7,7]
  const float* b2 = (const float*)d_in[4];   // [192]
  float* out = (float*)d_out;                // [64,192,8,8]

  uint32_t kp1a, kp1b, kp2a, kp2b;
  threefry2x32(0u, 42u, 0u, 0u, &kp1a, &kp1b);
  threefry2x32(0u, 42u, 0u, 1u, &kp2a, &kp2b);

  const size_t WSPL_BYTES = WSPLIT_ELEMS * 2ull;                 // 1,806,336
  const size_t need_main = H1F32_BYTES + CONV_BYTES + 3 * WSPL_BYTES +
                           16 + (size_t)REDO_CAP * 4;            // 55,980,048
  const size_t need_f64  = H1_BYTES;                             // 44,236,800
  const size_t need_hp   = H1F32_BYTES + 16 + (size_t)REDO_CAP * 4;

  if (ws_size >= need_main) {
    float* h1f32 = (float*)d_ws;
    float* conv  = (float*)((char*)d_ws + H1F32_BYTES);
    unsigned short* wp0 =
        (unsigned short*)((char*)d_ws + H1F32_BYTES + CONV_BYTES);
    unsigned short* wp1 = wp0 + WSPLIT_ELEMS;
    unsigned short* wp2 = wp1 + WSPLIT_ELEMS;
    unsigned int* cnt = (unsigned int*)((char*)d_ws + H1F32_BYTES + CONV_BYTES +
                                        3 * WSPL_BYTES);
    unsigned int* list = cnt + 4;
    w2_split_kernel<<<3528, 256, 0, stream>>>(W2, wp0, wp1, wp2);
    l1_kernel<<<dim3(96, 64, 2), 256, 0, stream>>>(
        x, W1, b1, (double*)0, h1f32, 0, 1, cnt, kp1a, kp1b);
    l2_mfma_kernel<<<dim3(3, 192), 256, 0, stream>>>(h1f32, wp0, wp1, wp2, conv);
    l2_pool_kernel<<<dim3(64, 64), 192, 0, stream>>>(conv, b2, out, cnt, list,
                                                     kp2a, kp2b);
    l2_redo_kernel<<<REDO_CAP, 64, 0, stream>>>(h1f32, W2, b2, out, cnt, list,
                                                kp2a, kp2b);
  } else if (ws_size >= need_f64) {
    double* h1 = (double*)d_ws;
    l1_kernel<<<dim3(96, 64, 2), 256, 0, stream>>>(
        x, W1, b1, h1, (float*)0, 1, 0, (unsigned int*)0, kp1a, kp1b);
    l2_kernel_f64<<<dim3(24, 64), 256, 0, stream>>>(h1, W2, b2, out,
                                                    kp2a, kp2b);
  } else {
    float* h1f32 = (float*)d_ws;
    unsigned int* cnt  = (unsigned int*)((char*)d_ws + H1F32_BYTES);
    unsigned int* list = cnt + 4;
    l1_kernel<<<dim3(96, 64, 2), 256, 0, stream>>>(
        x, W1, b1, (double*)0, h1f32, 0, 1, cnt, kp1a, kp1b);
    l2_kernel_hp<float><<<dim3(24, 64), 256, 0, stream>>>(
        h1f32, W2, b2, out, cnt, list, kp2a, kp2b);
    l2_redo_kernel<<<REDO_CAP, 64, 0, stream>>>(h1f32, W2, b2, out, cnt, list,
                                                kp2a, kp2b);
  }
}

// Round 4
// 932.392 us; speedup vs baseline: 1.9525x; 1.3622x over previous
//
#include <hip/hip_runtime.h>
#include <cstdint>
#include <math.h>

// ConvDBN R18: BOTH convs on MFMA (bf16x3 split, 6 products = f32-grade).
// R17 failed (absmax 0.997): corner OOB LDS read in l1_mfma -- k=28..31
// (kw=7 zero-weight pad) at x_local=29,row 11,plane 2,g=3 reads 8B past the
// 10,368-B A region into stale LDS; stale bf16 inf/NaN * 0 = NaN poisons
// conv pos 179, silently excluding k=8 from that pool argmax (NaN compares
// false) -> wrong winner, large gap, never flagged. R18 fix: (1) zero the
// 16B pad after the A region (OOB read then yields 0.0 * 0 = 0 as designed;
// audited: only that one corner overflows); (2) NaN-robust flag conditions
// (!(gap>=TAU) + NaN-sum check) in both pools -> any residual poisoning goes
// to exact-f64 redo. Everything else identical to R17: l1 GEMM M=positions,
// N=96, K=147 k-packed k=pix*4+ic (K=32 granule = 8 contiguous px, no im2col
// dup); A 12x36x4x3planes LDS via global_load_lds from pre-split x; B direct
// global [kh][pl][oc][32]; C->LDS (stride 98), in-kernel f32 gumbel pool
// (threefry bits exact) + TAU1=2e-3 -> l1_redo exact-f64. l2 path = R16
// (verified). Workspace: conv aliases dead x-split region, 56.1MB.

#define EPS_D 1e-8
#define INV_SIGMA2 (1.0 / (0.2 * 0.2))
#define TAU 6e-3
#define TAU1 2e-3f
#define REDO_CAP 32768
#define H1_BYTES (5529600ull * 8ull)
#define H1F32_BYTES (5529600ull * 4ull)
#define CONV_BYTES (64ull * 576ull * 192ull * 4ull)
#define WSPLIT_ELEMS (49ull * 192ull * 96ull)
#define XSPL_PLANE 2359296ull            // elems per x-split plane
#define XSPL_BYTES (3ull * XSPL_PLANE * 2ull)
#define W1B_ELEMS (7ull * 3ull * 96ull * 32ull)

typedef __bf16 bf16x8 __attribute__((ext_vector_type(8)));
typedef __bf16 bf16x4 __attribute__((ext_vector_type(4)));
typedef float f32x4 __attribute__((ext_vector_type(4)));

#define MFMA(A_, B_, C_) \
  __builtin_amdgcn_mfma_f32_16x16x32_bf16((A_), (B_), (C_), 0, 0, 0)

__host__ __device__ __forceinline__ void threefry2x32(
    uint32_t k0, uint32_t k1, uint32_t x0, uint32_t x1,
    uint32_t* o0, uint32_t* o1) {
  const uint32_t ks0 = k0, ks1 = k1, ks2 = k0 ^ k1 ^ 0x1BD11BDAu;
  x0 += ks0; x1 += ks1;
#define TF_R(r) { x0 += x1; x1 = (x1 << (r)) | (x1 >> (32 - (r))); x1 ^= x0; }
  TF_R(13) TF_R(15) TF_R(26) TF_R(6)
  x0 += ks1; x1 += ks2 + 1u;
  TF_R(17) TF_R(29) TF_R(16) TF_R(24)
  x0 += ks2; x1 += ks0 + 2u;
  TF_R(13) TF_R(15) TF_R(26) TF_R(6)
  x0 += ks0; x1 += ks1 + 3u;
  TF_R(17) TF_R(29) TF_R(16) TF_R(24)
  x0 += ks1; x1 += ks2 + 4u;
  TF_R(13) TF_R(15) TF_R(26) TF_R(6)
  x0 += ks2; x1 += ks0 + 5u;
#undef TF_R
  *o0 = x0; *o1 = x1;
}

__device__ __forceinline__ double fast_log(double x) {
  long long ib = __double_as_longlong(x);
  int e = (int)((ib >> 52) & 0x7ff) - 1023;
  double r = __longlong_as_double((ib & 0xfffffffffffffLL) | 0x3ff0000000000000LL);
  if (r > 1.4142135623730951) { r *= 0.5; e += 1; }
  double s = (r - 1.0) / (r + 1.0);
  double s2 = s * s;
  double t = fma(s2, fma(s2, fma(s2, fma(s2, fma(s2, fma(s2,
      1.0/15.0, 1.0/13.0), 1.0/11.0), 1.0/9.0), 1.0/7.0), 1.0/5.0), 1.0/3.0);
  double lr = fma(2.0 * s * s2, t, 2.0 * s);
  return fma((double)e, 0.6931471805599453, lr);
}

__device__ __forceinline__ double fast_exp(double x) {
  double nd = rint(x * 1.4426950408889634);
  double f = fma(nd, -0.6931471803691238, x);
  f = fma(nd, -1.9082149292705877e-10, f);
  double p = 2.505210838544172e-8;
  p = fma(p, f, 2.755731922398589e-7);
  p = fma(p, f, 2.7557319223985893e-6);
  p = fma(p, f, 2.48015873015873e-5);
  p = fma(p, f, 1.984126984126984e-4);
  p = fma(p, f, 1.3888888888888889e-3);
  p = fma(p, f, 8.333333333333333e-3);
  p = fma(p, f, 4.1666666666666664e-2);
  p = fma(p, f, 0.16666666666666666);
  p = fma(p, f, 0.5);
  p = fma(p, f, 1.0);
  p = fma(p, f, 1.0);
  return ldexp(p, (int)nd);
}

__device__ __forceinline__ double gumbel_pool9(const double (&acc)[9],
                                               double bb, uint64_t base,
                                               uint32_t kp0, uint32_t kp1) {
  double bestv = -1e308, bA = 1.0, bQ = 0.0;
#pragma unroll
  for (int k = 0; k < 9; ++k) {
    double pre = (acc[k] + bb) * INV_SIGMA2;
    double q = fast_exp(-fabs(pre));
    double A = pre >= 0.0 ? 1.0 : q;          // p = A/(1+q)
    double opq = 1.0 + q;
    double L = fast_log(fma(EPS_D, opq, A)) - fast_log(opq);
    uint32_t o0, o1;
    uint64_t idx = base + (uint64_t)k;
    threefry2x32(kp0, kp1, (uint32_t)(idx >> 32), (uint32_t)idx, &o0, &o1);
    uint32_t bits = o0 ^ o1;
    float u = __uint_as_float((bits >> 9) | 0x3f800000u) - 1.0f;
    if (u == 0.0f) u = 1.17549435e-38f;
    float lg1 = (float)fast_log((double)u);
    double lg2 = fast_log(-(double)lg1);
    float gf = -(float)lg2;
    double v = L + (double)gf;
    if (v > bestv) { bestv = v; bA = A; bQ = q; }   // first-occurrence argmax
  }
  return bA / (1.0 + bQ);
}

__device__ __forceinline__ double gumbel_pool9_gap(const double (&acc)[9],
                                                   double bb, uint64_t base,
                                                   uint32_t kp0, uint32_t kp1,
                                                   double* gap) {
  double bestv = -1e308, second = -1e308, bA = 1.0, bQ = 0.0;
#pragma unroll
  for (int k = 0; k < 9; ++k) {
    double pre = (acc[k] + bb) * INV_SIGMA2;
    double q = fast_exp(-fabs(pre));
    double A = pre >= 0.0 ? 1.0 : q;
    double opq = 1.0 + q;
    double L = fast_log(fma(EPS_D, opq, A)) - fast_log(opq);
    uint32_t o0, o1;
    uint64_t idx = base + (uint64_t)k;
    threefry2x32(kp0, kp1, (uint32_t)(idx >> 32), (uint32_t)idx, &o0, &o1);
    uint32_t bits = o0 ^ o1;
    float u = __uint_as_float((bits >> 9) | 0x3f800000u) - 1.0f;
    if (u == 0.0f) u = 1.17549435e-38f;
    float lg1 = (float)fast_log((double)u);
    double lg2 = fast_log(-(double)lg1);
    float gf = -(float)lg2;
    double v = L + (double)gf;
    if (v > bestv) { second = bestv; bestv = v; bA = A; bQ = q; }
    else if (v > second) second = v;
  }
  *gap = bestv - second;
  return bA / (1.0 + bQ);
}

// f32 main-path pool (decisions protected by TAU1 redo; threefry bits exact)
__device__ __forceinline__ float gumbel_pool9_gap_f32(
    const float (&acc)[9], float bb, uint64_t base,
    uint32_t kp0, uint32_t kp1, float* gap) {
  float bestv = -1e30f, second = -1e30f, bA = 1.0f, bQ = 0.0f;
#pragma unroll
  for (int k = 0; k < 9; ++k) {
    float pre = (acc[k] + bb) * 25.0f;
    float q = __expf(-fabsf(pre));
    float A = pre >= 0.0f ? 1.0f : q;
    float opq = 1.0f + q;
    float L = __logf(fmaf(1e-8f, opq, A)) - __logf(opq);
    uint32_t o0, o1;
    uint64_t idx = base + (uint64_t)k;
    threefry2x32(kp0, kp1, (uint32_t)(idx >> 32), (uint32_t)idx, &o0, &o1);
    uint32_t bits = o0 ^ o1;
    float u = __uint_as_float((bits >> 9) | 0x3f800000u) - 1.0f;
    if (u == 0.0f) u = 1.17549435e-38f;
    float lg1 = __logf(u);
    float gf = -__logf(-lg1);
    float v = L + gf;
    if (v > bestv) { second = bestv; bestv = v; bA = A; bQ = q; }
    else if (v > second) second = v;
  }
  *gap = bestv - second;
  return bA / (1.0f + bQ);
}

__device__ __forceinline__ unsigned short f32_to_bf16(float v) {
  uint32_t u = __float_as_uint(v);
  return (unsigned short)((u + 0x7fffu + ((u >> 16) & 1u)) >> 16);
}
__device__ __forceinline__ float bf16_to_f32(unsigned short s) {
  return __uint_as_float(((uint32_t)s) << 16);
}

// ---- f64 vertical output pair (fallback l1/l2; R8-verified) ----
template <int LDSTRIDE, typename T>
__device__ __forceinline__ void conv_pair(const T* __restrict__ xb,
                                          const double (&w)[49],
                                          double (&a0)[9], double (&a1)[9]) {
#pragma unroll
  for (int pr = 0; pr < 12; ++pr) {
    double xr[9];
#pragma unroll
    for (int c = 0; c < 9; ++c) xr[c] = (double)xb[pr * LDSTRIDE + c];
#pragma unroll
    for (int ki = 0; ki < 3; ++ki) {
      const int u0 = pr - ki;
      if (u0 >= 0 && u0 <= 6) {
#pragma unroll
        for (int kj = 0; kj < 3; ++kj)
#pragma unroll
          for (int v = 0; v < 7; ++v)
            a0[ki * 3 + kj] = fma(xr[kj + v], w[u0 * 7 + v], a0[ki * 3 + kj]);
      }
      const int u1 = pr - 3 - ki;
      if (u1 >= 0 && u1 <= 6) {
#pragma unroll
        for (int kj = 0; kj < 3; ++kj)
#pragma unroll
          for (int v = 0; v < 7; ++v)
            a1[ki * 3 + kj] = fma(xr[kj + v], w[u1 * 7 + v], a1[ki * 3 + kj]);
      }
    }
  }
}

// ---------------- counter init ----------------
__global__ void init_cnt_kernel(unsigned int* __restrict__ cnt) {
  cnt[0] = 0u; cnt[1] = 0u;
}

// ---------------- Layer 1 fallback (f64, R8-verified) ----------------------
__global__ __launch_bounds__(256, 3) void l1_kernel(
    const float* __restrict__ x, const float* __restrict__ W1,
    const float* __restrict__ b1, double* __restrict__ h1,
    float* __restrict__ h1f32, int write_f64, int write_f32,
    unsigned int* __restrict__ cnt, uint32_t kp0, uint32_t kp1) {
  const int oc   = blockIdx.x;   // 96
  const int b    = blockIdx.y;   // 64
  const int half = blockIdx.z;   // 2
  const int t = threadIdx.x;
  const int wave = t >> 6;

  if (cnt && oc == 0 && b == 0 && half == 0 && t == 0) *cnt = 0u;

  __shared__ float xs[54 * 96];   // 20,736 B

  const int p0 = 14 * half;
  const bool active = t < 240;
  const int q = t / 30, bw = t - q * 30;
  const float* xb = xs + (6 * q) * 96 + 3 * bw;

  double a0[9] = {}, a1[9] = {};
  double w[49];

#pragma unroll 1
  for (int ic = 0; ic < 3; ++ic) {
    __syncthreads();
    {
      const char* gsrc = (const char*)(x + ((size_t)b * 3 + ic) * 9216 + (3 * p0) * 96);
#pragma unroll
      for (int p = 0; p < 6; ++p) {
        int elt = p * 256 + t;
        if (elt < 1296) {
          __builtin_amdgcn_global_load_lds(
              (const __attribute__((address_space(1))) void*)(gsrc + (size_t)elt * 16),
              (__attribute__((address_space(3))) void*)((char*)xs +
                                                        (size_t)(p * 256 + wave * 64) * 16),
              16, 0, 0);
        }
      }
    }
    __syncthreads();
    {
      const float* __restrict__ wsrc = W1 + (oc * 3 + ic) * 49;
#pragma unroll
      for (int j = 0; j < 49; ++j) w[j] = (double)wsrc[j];
    }
    if (active) conv_pair<96, float>(xb, w, a0, a1);
  }

  if (active) {
    const double bb = (double)b1[oc];
    const int bh0 = p0 + 2 * q;
#pragma unroll
    for (int j = 0; j < 2; ++j) {
      const int pos = (bh0 + j) * 30 + bw;
      const uint64_t base = ((uint64_t)((b * 96 + oc) * 900 + pos)) * 9ull;
      double pooled = gumbel_pool9(j ? a1 : a0, bb, base, kp0, kp1);
      const size_t oidx = (size_t)(b * 96 + oc) * 900 + pos;
      if (write_f64) h1[oidx] = pooled;
      if (write_f32) h1f32[oidx] = (float)pooled;
    }
  }
}

// ---------------- x bf16x3 split: [b][ic][row][px] -> [pl][b][row][px][4] ---
__global__ __launch_bounds__(256) void x_split_kernel(
    const float* __restrict__ x, unsigned short* __restrict__ xs) {
  int idx = blockIdx.x * 256 + threadIdx.x;   // 589824 = 2304*256 exact
  int px = idx % 96; int rest = idx / 96;
  int row = rest % 96; int b = rest / 96;
  unsigned long long pk[3] = {0ull, 0ull, 0ull};
#pragma unroll
  for (int ic = 0; ic < 3; ++ic) {
    float v = x[((size_t)(b * 3 + ic) * 96 + row) * 96 + px];
    unsigned short s0 = f32_to_bf16(v); float r1 = v - bf16_to_f32(s0);
    unsigned short s1 = f32_to_bf16(r1); float r2 = r1 - bf16_to_f32(s1);
    unsigned short s2 = f32_to_bf16(r2);
    pk[0] |= (unsigned long long)s0 << (16 * ic);
    pk[1] |= (unsigned long long)s1 << (16 * ic);
    pk[2] |= (unsigned long long)s2 << (16 * ic);
  }
#pragma unroll
  for (int p = 0; p < 3; ++p)
    *(unsigned long long*)(xs + (size_t)p * XSPL_PLANE + (size_t)idx * 4) = pk[p];
}

// ---------------- W1 bf16x3 split: -> [kh][pl][oc][32], k=kw*4+ic ----------
__global__ __launch_bounds__(256) void w1_split_kernel(
    const float* __restrict__ W1, unsigned short* __restrict__ wb) {
  int idx = blockIdx.x * 256 + threadIdx.x;   // 21504 = 84*256 exact
  int k = idx % 32; int rest = idx / 32;
  int oc = rest % 96; int kh = rest / 96;
  int kw = k >> 2, ic = k & 3;
  float v = (ic < 3 && kw < 7) ? W1[(((size_t)oc * 3 + ic) * 7 + kh) * 7 + kw] : 0.0f;
  unsigned short a = f32_to_bf16(v); float r1 = v - bf16_to_f32(a);
  unsigned short b = f32_to_bf16(r1); float r2 = r1 - bf16_to_f32(b);
  unsigned short c = f32_to_bf16(r2);
  wb[((size_t)(kh * 3 + 0) * 96 + oc) * 32 + k] = a;
  wb[((size_t)(kh * 3 + 1) * 96 + oc) * 32 + k] = b;
  wb[((size_t)(kh * 3 + 2) * 96 + oc) * 32 + k] = c;
}

// ---------------- W2 bf16x3 split: [oc][ic][tap] f32 -> [tap][oc][ic] ------
__global__ __launch_bounds__(256) void w2_split_kernel(
    const float* __restrict__ W2, unsigned short* __restrict__ s0,
    unsigned short* __restrict__ s1, unsigned short* __restrict__ s2) {
  int idx = blockIdx.x * 256 + threadIdx.x;      // 903168 = 3528*256 exact
  int ic = idx % 96; int rest = idx / 96;
  int oc = rest % 192; int tap = rest / 192;
  float v = W2[(size_t)(oc * 96 + ic) * 49 + tap];
  unsigned short a = f32_to_bf16(v); float r1 = v - bf16_to_f32(a);
  unsigned short b = f32_to_bf16(r1); float r2 = r1 - bf16_to_f32(b);
  unsigned short c = f32_to_bf16(r2);
  s0[idx] = a; s1[idx] = b; s2[idx] = c;
}

// ---------------- Layer 1 conv+pool via MFMA (bf16x3) ----------------------
// Block: 6 conv rows x 30 cols (M=180 pad 192), N=96 oc. 4 waves split 4M.
// k-pack k=pix*4+ic: K=32 granule = 8 contiguous pixels; kh-loop 7 granules.
// A: LDS 12rows x 36px x 4 x bf16 x 3 planes (10,368 B + 16B ZERO PAD),
// staged via global_load_lds from pre-split x. B: direct global.
// Epilogue: C->LDS dump (stride 98), f32 gumbel pool + TAU1 flags.
__global__ __launch_bounds__(256, 2) void l1_mfma_kernel(
    const unsigned short* __restrict__ xs, const unsigned short* __restrict__ wb,
    const float* __restrict__ b1, float* __restrict__ h1f32,
    unsigned int* __restrict__ cnt, unsigned int* __restrict__ list,
    uint32_t kp0, uint32_t kp1) {
  const int xt = blockIdx.x;       // 0..2
  const int yt = blockIdx.y;       // 0..14
  const int b  = blockIdx.z;       // 0..63
  const int t = threadIdx.x;
  const int w = t >> 6;            // wave = M-split 0..3
  const int l = t & 63;
  const int g = l >> 4;
  const int lr = l & 15;
  const int x0 = 30 * xt;
  const int y0 = 6 * yt;

  __shared__ __align__(16) float smem_f[17640];   // 70,560 B: A(10,368+16 pad) then conv[180][98]
  char* smem = (char*)smem_f;

  // R18 FIX: zero the 16B pad after the A region. The kw=7 (B=0) k-slots at
  // row 11, x=29, g=3, plane 2 read bytes 10368..10375; stale inf/NaN there
  // made 0*inf=NaN and silently dropped k=8 from the pool argmax (R17 bug).
  if (t < 4) smem_f[2592 + t] = 0.0f;

  // ---- stage A: 648 x 16B
  {
    const int wave64 = w << 6;
#pragma unroll
    for (int p = 0; p < 3; ++p) {
      int s = p * 256 + t;
      if (s < 648) {
        int pl = s / 216;
        int r2 = s - pl * 216;
        int row = r2 / 18;
        int ch = r2 - row * 18;
        const char* src = (const char*)(xs + (size_t)pl * XSPL_PLANE +
                          ((size_t)((b * 96 + y0 + row) * 96 + x0)) * 4) + ch * 16;
        __builtin_amdgcn_global_load_lds(
            (const __attribute__((address_space(1))) void*)src,
            (__attribute__((address_space(3))) void*)(smem + (size_t)(p * 256 + wave64) * 16),
            16, 0, 0);
      }
    }
  }

  int aoff[3];
#pragma unroll
  for (int mf = 0; mf < 3; ++mf) {
    int pos = (w * 3 + mf) * 16 + lr;
    if (pos > 179) pos = 179;                 // pad rows: duplicate, discarded
    int ya = pos / 30, xxa = pos - 30 * ya;
    aoff[mf] = ya * 288 + xxa * 8 + g * 16;   // + kh*288 + plane*3456
  }

  f32x4 acc[3][6];
#pragma unroll
  for (int mf = 0; mf < 3; ++mf)
#pragma unroll
    for (int nf = 0; nf < 6; ++nf) acc[mf][nf] = (f32x4){0.f, 0.f, 0.f, 0.f};

  __syncthreads();

#pragma unroll 1
  for (int kh = 0; kh < 7; ++kh) {
    bf16x8 bc[6][3];
#pragma unroll
    for (int nf = 0; nf < 6; ++nf) {
      int oc = nf * 16 + lr;
#pragma unroll
      for (int pl = 0; pl < 3; ++pl)
        bc[nf][pl] = *(const bf16x8*)&wb[(((size_t)kh * 3 + pl) * 96 + oc) * 32 + 8 * g];
    }
#pragma unroll
    for (int mf = 0; mf < 3; ++mf) {
      const char* ap = smem + kh * 288 + aoff[mf];
      bf16x4 a0l = *(const bf16x4*)(ap);
      bf16x4 a0h = *(const bf16x4*)(ap + 8);
      bf16x4 a1l = *(const bf16x4*)(ap + 3456);
      bf16x4 a1h = *(const bf16x4*)(ap + 3464);
      bf16x4 a2l = *(const bf16x4*)(ap + 6912);
      bf16x4 a2h = *(const bf16x4*)(ap + 6920);
      bf16x8 a0 = __builtin_shufflevector(a0l, a0h, 0, 1, 2, 3, 4, 5, 6, 7);
      bf16x8 a1 = __builtin_shufflevector(a1l, a1h, 0, 1, 2, 3, 4, 5, 6, 7);
      bf16x8 a2 = __builtin_shufflevector(a2l, a2h, 0, 1, 2, 3, 4, 5, 6, 7);
#pragma unroll
      for (int nf = 0; nf < 6; ++nf) {
        f32x4 c = acc[mf][nf];
        c = MFMA(a0, bc[nf][0], c);
        c = MFMA(a0, bc[nf][1], c);
        c = MFMA(a1, bc[nf][0], c);
        c = MFMA(a1, bc[nf][1], c);
        c = MFMA(a0, bc[nf][2], c);
        c = MFMA(a2, bc[nf][0], c);
        acc[mf][nf] = c;
      }
    }
  }

  __syncthreads();   // all A reads done; overlay dump
  {
#pragma unroll
    for (int mf = 0; mf < 3; ++mf)
#pragma unroll
      for (int nf = 0; nf < 6; ++nf)
#pragma unroll
        for (int r = 0; r < 4; ++r) {
          int pos = (w * 3 + mf) * 16 + g * 4 + r;
          if (pos < 180) smem_f[pos * 98 + nf * 16 + lr] = acc[mf][nf][r];
        }
  }
  __syncthreads();

  // ---- pool: 2 pool-rows x 10 cols x 96 oc = 1920 outputs
#pragma unroll 1
  for (int i = 0; i < 8; ++i) {
    int oi = i * 256 + t;
    if (oi < 1920) {
      int oc = oi % 96; int rc = oi / 96;
      int pc = rc % 10, pr = rc / 10;
      float a[9];
      float chk = 0.0f;
#pragma unroll
      for (int dy = 0; dy < 3; ++dy)
#pragma unroll
        for (int dx = 0; dx < 3; ++dx) {
          float v = smem_f[((pr * 3 + dy) * 30 + pc * 3 + dx) * 98 + oc];
          a[dy * 3 + dx] = v;
          chk += v;
        }
      int gy = yt * 2 + pr, gx = xt * 10 + pc;
      unsigned int oidx = (unsigned int)((b * 96 + oc) * 900 + gy * 30 + gx);
      float gap;
      float pooled = gumbel_pool9_gap_f32(a, b1[oc], (uint64_t)oidx * 9ull,
                                          kp0, kp1, &gap);
      h1f32[oidx] = pooled;
      if (!(gap >= TAU1) || chk != chk) {   // NaN-robust: NaN gap/acc -> redo
        unsigned int idx = atomicAdd(cnt, 1u);
        if (idx < REDO_CAP) list[idx] = oidx;
      }
    }
  }
}

// ---------------- Layer 1 tie-redo (exact f64 from x, W1) ------------------
__global__ __launch_bounds__(64) void l1_redo_kernel(
    const float* __restrict__ x, const float* __restrict__ W1,
    const float* __restrict__ b1, float* __restrict__ h1f32,
    const unsigned int* __restrict__ cnt, const unsigned int* __restrict__ list,
    uint32_t kp0, uint32_t kp1) {
  unsigned int n = *cnt;
  if (n > REDO_CAP) n = REDO_CAP;
  if (blockIdx.x >= n) return;
  const unsigned int oidx = list[blockIdx.x];
  const int gx = oidx % 30;
  const int gy = (oidx / 30) % 30;
  const int rest = oidx / 900;
  const int oc = rest % 96, b = rest / 96;
  const int lane = threadIdx.x;

  double acc[9] = {};
  if (lane < 49) {
    const int kh = lane / 7, kw = lane % 7;
#pragma unroll
    for (int ic = 0; ic < 3; ++ic) {
      double wv = (double)W1[(((size_t)oc * 3 + ic) * 7 + kh) * 7 + kw];
      const float* __restrict__ xp = x + ((size_t)(b * 3 + ic) * 96) * 96;
#pragma unroll
      for (int dy = 0; dy < 3; ++dy)
#pragma unroll
        for (int dx = 0; dx < 3; ++dx) {
          int y = 3 * gy + dy + kh, xc = 3 * gx + dx + kw;
          acc[dy * 3 + dx] = fma((double)xp[(size_t)y * 96 + xc], wv, acc[dy * 3 + dx]);
        }
    }
  }
#pragma unroll
  for (int off = 32; off; off >>= 1)
#pragma unroll
    for (int k = 0; k < 9; ++k) acc[k] += __shfl_down(acc[k], off);

  if (lane == 0) {
    double pooled = gumbel_pool9(acc, (double)b1[oc], (uint64_t)oidx * 9ull,
                                 kp0, kp1);
    h1f32[oidx] = (float)pooled;
  }
}

// ---------------- Layer 2 conv via MFMA (bf16x3; R16-verified) -------------
__global__ __launch_bounds__(256, 1) void l2_mfma_kernel(
    const float* __restrict__ h1f32, const unsigned short* __restrict__ wp0,
    const unsigned short* __restrict__ wp1,
    const unsigned short* __restrict__ wp2, float* __restrict__ conv) {
  const int nt = blockIdx.x;            // 0..2  (N-tile: 64 oc)
  const int my = blockIdx.y;            // 0..191 = b*3 + mt
  const int b = my / 3, mt = my - 3 * b;
  const int t = threadIdx.x;
  const int l = t & 63;
  const int w = t >> 6;
  const int wm = w >> 1, wn = w & 1;
  const int g = l >> 4;                 // 0..3 (k-granule)
  const int lr = l & 15;                // A-row / B-col lane index

  __shared__ unsigned short As[3 * 4 * 14 * 30 * 8];   // 80,640 B

  int rowoff[6];
#pragma unroll
  for (int mf = 0; mf < 6; ++mf) {
    int ml = wm * 96 + mf * 16 + lr;    // 0..191
    int yl = ml / 24, xx = ml - 24 * yl;
    rowoff[mf] = g * 3360 + (yl * 30 + xx) * 8;
  }
  const int oc0 = nt * 64 + wn * 32 + lr;

  f32x4 acc[6][2];
#pragma unroll
  for (int mf = 0; mf < 6; ++mf)
#pragma unroll
    for (int nf = 0; nf < 2; ++nf) acc[mf][nf] = (f32x4){0.f, 0.f, 0.f, 0.f};

#pragma unroll 1
  for (int ch = 0; ch < 3; ++ch) {
    __syncthreads();
    {
      const float* __restrict__ hb =
          h1f32 + ((size_t)b * 96 + ch * 32) * 900 + (8 * mt) * 30;
#pragma unroll 1
      for (int idx = t; idx < 13440; idx += 256) {
        int i = idx / 420, rem = idx - i * 420;   // i = ic-local, rem = r*30+x
        float v = hb[(size_t)i * 900 + rem];
        unsigned short p0 = f32_to_bf16(v);
        float r1 = v - bf16_to_f32(p0);
        unsigned short p1 = f32_to_bf16(r1);
        float r2 = r1 - bf16_to_f32(p1);
        unsigned short p2 = f32_to_bf16(r2);
        int base = (i >> 3) * 3360 + rem * 8 + (i & 7);
        As[base] = p0; As[base + 13440] = p1; As[base + 26880] = p2;
      }
    }
    __syncthreads();

    int boff = oc0 * 96 + ch * 32 + 8 * g;   // elem index; +18432/tap
    bf16x8 bc[2][3], bn[2][3];
#pragma unroll
    for (int nf = 0; nf < 2; ++nf) {
      bc[nf][0] = *(const bf16x8*)&wp0[boff + nf * 1536];
      bc[nf][1] = *(const bf16x8*)&wp1[boff + nf * 1536];
      bc[nf][2] = *(const bf16x8*)&wp2[boff + nf * 1536];
    }
    int kh = 0, kw = 0;
#pragma unroll 1
    for (int tap = 0; tap < 49; ++tap) {
      if (tap < 48) {
        const int bo2 = boff + 18432;
#pragma unroll
        for (int nf = 0; nf < 2; ++nf) {
          bn[nf][0] = *(const bf16x8*)&wp0[bo2 + nf * 1536];
          bn[nf][1] = *(const bf16x8*)&wp1[bo2 + nf * 1536];
          bn[nf][2] = *(const bf16x8*)&wp2[bo2 + nf * 1536];
        }
        boff = bo2;
      }
      const int tapoff = (kh * 30 + kw) * 8;
#pragma unroll
      for (int mf = 0; mf < 6; ++mf) {
        const int ab = rowoff[mf] + tapoff;
        bf16x8 a0 = *(const bf16x8*)&As[ab];
        bf16x8 a1 = *(const bf16x8*)&As[ab + 13440];
        bf16x8 a2 = *(const bf16x8*)&As[ab + 26880];
#pragma unroll
        for (int nf = 0; nf < 2; ++nf) {
          f32x4 c = acc[mf][nf];
          c = MFMA(a0, bc[nf][0], c);
          c = MFMA(a0, bc[nf][1], c);
          c = MFMA(a1, bc[nf][0], c);
          c = MFMA(a1, bc[nf][1], c);
          c = MFMA(a0, bc[nf][2], c);
          c = MFMA(a2, bc[nf][0], c);
          acc[mf][nf] = c;
        }
      }
      if (tap < 48) {
#pragma unroll
        for (int nf = 0; nf < 2; ++nf)
#pragma unroll
          for (int s = 0; s < 3; ++s) bc[nf][s] = bn[nf][s];
      }
      if (++kw == 7) { kw = 0; ++kh; }
    }
  }

  const int rowsub = g * 4;
#pragma unroll
  for (int mf = 0; mf < 6; ++mf)
#pragma unroll
    for (int nf = 0; nf < 2; ++nf)
#pragma unroll
      for (int r = 0; r < 4; ++r) {
        const int m_abs = mt * 192 + wm * 96 + mf * 16 + rowsub + r;
        const int oc = oc0 + nf * 16;
        conv[((size_t)b * 576 + m_abs) * 192 + oc] = acc[mf][nf][r];
      }
}

// ---------------- Layer 2 pool (gumbel + gap flags from conv buffer) -------
__global__ __launch_bounds__(192) void l2_pool_kernel(
    const float* __restrict__ conv, const float* __restrict__ b2,
    float* __restrict__ out, unsigned int* __restrict__ cnt,
    unsigned int* __restrict__ list, uint32_t kp0, uint32_t kp1) {
  const int pos = blockIdx.x;   // 0..63 = ph*8+pw
  const int b = blockIdx.y;     // 64
  const int oc = threadIdx.x;   // 192
  const int ph = pos >> 3, pw = pos & 7;
  double a[9];
  double chk = 0.0;
  const float* __restrict__ cb = conv + (size_t)b * 576 * 192 + oc;
#pragma unroll
  for (int dy = 0; dy < 3; ++dy)
#pragma unroll
    for (int dx = 0; dx < 3; ++dx) {
      double v = (double)cb[((size_t)((3 * ph + dy) * 24 + 3 * pw + dx)) * 192];
      a[dy * 3 + dx] = v;
      chk += v;
    }
  const unsigned int oid = (unsigned int)((b * 192 + oc) * 64 + pos);
  double gap;
  double pooled = gumbel_pool9_gap(a, (double)b2[oc], (uint64_t)oid * 9ull,
                                   kp0, kp1, &gap);
  out[oid] = (float)pooled;
  if (!(gap >= TAU) || chk != chk) {   // NaN-robust
    unsigned int idx = atomicAdd(cnt, 1u);
    if (idx < REDO_CAP) list[idx] = oid;
  }
}

// ---------------- Layer 2 fallback (pure f64, R8-verified) -----------------
__global__ __launch_bounds__(256, 3) void l2_kernel_f64(
    const double* __restrict__ h1, const float* __restrict__ W2,
    const float* __restrict__ b2, float* __restrict__ out,
    uint32_t kp0, uint32_t kp1) {
  const int octile = blockIdx.x;
  const int b      = blockIdx.y;
  const int t = threadIdx.x;
  const int wave = t >> 6;
  const int oc_local = t >> 5;
  const int li = t & 31;
  const int bw = li & 7;
  const int ph = 2 * ((li >> 3) & 1) + (li >> 4);
  const int bh0 = 2 * ph;
  const int oc = octile * 8 + oc_local;

  __shared__ double hs[2][900];
  __shared__ double wsd[2][392];

  const double* __restrict__ hb = h1 + (size_t)b * 86400;
  const float* __restrict__ wg = W2 + (size_t)octile * 8 * 4704;

  double a0[9] = {}, a1[9] = {};
  double w[49];

  auto stage = [&](int c, int buf) {
    const char* gsrc = (const char*)(hb + (size_t)c * 900);
#pragma unroll
    for (int p = 0; p < 2; ++p) {
      int elt = p * 256 + t;
      if (elt < 450) {
        __builtin_amdgcn_global_load_lds(
            (const __attribute__((address_space(1))) void*)(gsrc + (size_t)elt * 16),
            (__attribute__((address_space(3))) void*)((char*)&hs[buf][0] +
                                                      (size_t)(p * 256 + wave * 64) * 16),
            16, 0, 0);
      }
    }
#pragma unroll
    for (int p = 0; p < 2; ++p) {
      int j = p * 256 + t;
      if (j < 392) {
        int oi = j / 49, rem = j - oi * 49;
        wsd[buf][j] = (double)wg[(size_t)oi * 4704 + c * 49 + rem];
      }
    }
  };

  stage(0, 0);
#pragma unroll 1
  for (int c = 0; c < 96; ++c) {
    __syncthreads();
    if (c + 1 < 96) stage(c + 1, (c + 1) & 1);
    {
      const double* __restrict__ wsrc = &wsd[c & 1][oc_local * 49];
#pragma unroll
      for (int j = 0; j < 49; ++j) w[j] = wsrc[j];
      const double* xb = &hs[c & 1][(6 * ph) * 30 + 3 * bw];
      conv_pair<30, double>(xb, w, a0, a1);
    }
  }

  const double bb = (double)b2[oc];
#pragma unroll
  for (int j = 0; j < 2; ++j) {
    const int bh = bh0 + j;
    const uint64_t base = ((uint64_t)(((b * 192 + oc) * 8 + bh) * 8 + bw)) * 9ull;
    double pooled = gumbel_pool9(j ? a1 : a0, bb, base, kp0, kp1);
    out[(size_t)(b * 192 + oc) * 64 + bh * 8 + bw] = (float)pooled;
  }
}

// ---------------- Layer 2 tie-redo (exact f64 from h1f32) ------------------
__global__ __launch_bounds__(64) void l2_redo_kernel(
    const float* __restrict__ h1f, const float* __restrict__ W2,
    const float* __restrict__ b2, float* __restrict__ out,
    const unsigned int* __restrict__ cnt, const unsigned int* __restrict__ list,
    uint32_t kp0, uint32_t kp1) {
  unsigned int n = *cnt;
  if (n > REDO_CAP) n = REDO_CAP;
  if (blockIdx.x >= n) return;
  const unsigned int oid = list[blockIdx.x];
  const int sp = oid & 63, bh = sp >> 3, bw = sp & 7;
  const int rest = oid >> 6, oc = rest % 192, b = rest / 192;
  const int lane = threadIdx.x;

  double acc[9] = {};
  for (int ic = lane; ic < 96; ic += 64) {
    const float* __restrict__ xp =
        h1f + ((size_t)(b * 96 + ic) * 30 + 3 * bh) * 30 + 3 * bw;
    const float* __restrict__ wp = W2 + ((size_t)oc * 96 + ic) * 49;
    double w[49];
#pragma unroll
    for (int j = 0; j < 49; ++j) w[j] = (double)wp[j];
#pragma unroll
    for (int pr = 0; pr < 9; ++pr) {
      double xr[9];
#pragma unroll
      for (int c = 0; c < 9; ++c) xr[c] = (double)xp[pr * 30 + c];
#pragma unroll
      for (int kh = 0; kh < 3; ++kh) {
        const int u = pr - kh;
        if (u >= 0 && u <= 6) {
#pragma unroll
          for (int kw = 0; kw < 3; ++kw)
#pragma unroll
            for (int v = 0; v < 7; ++v)
              acc[kh * 3 + kw] = fma(xr[kw + v], w[u * 7 + v], acc[kh * 3 + kw]);
        }
      }
    }
  }
#pragma unroll
  for (int off = 32; off; off >>= 1)
#pragma unroll
    for (int k = 0; k < 9; ++k) acc[k] += __shfl_down(acc[k], off);

  if (lane == 0) {
    const uint64_t base = (uint64_t)oid * 9ull;
    double pooled = gumbel_pool9(acc, (double)b2[oc], base, kp0, kp1);
    out[oid] = (float)pooled;
  }
}

extern "C" void kernel_launch(void* const* d_in, const int* in_sizes, int n_in,
                              void* d_out, int out_size, void* d_ws,
                              size_t ws_size, hipStream_t stream) {
  const float* x  = (const float*)d_in[0];   // [64,3,96,96]
  const float* W1 = (const float*)d_in[1];   // [96,3,7,7]
  const float* b1 = (const float*)d_in[2];   // [96]
  const float* W2 = (const float*)d_in[3];   // [192,96,7,7]
  const float* b2 = (const float*)d_in[4];   // [192]
  float* out = (float*)d_out;                // [64,192,8,8]

  uint32_t kp1a, kp1b, kp2a, kp2b;
  threefry2x32(0u, 42u, 0u, 0u, &kp1a, &kp1b);
  threefry2x32(0u, 42u, 0u, 1u, &kp2a, &kp2b);

  const size_t WSPL_BYTES = WSPLIT_ELEMS * 2ull;
  // layout: [h1f32 | union(xsplit+w1b, conv) | w2 splits | cnt(16B) | list1 | list2]
  const size_t need_main = H1F32_BYTES + CONV_BYTES + 3 * WSPL_BYTES +
                           16 + 2 * (size_t)REDO_CAP * 4;   // 56,111,120
  const size_t need_f64  = H1_BYTES;

  if (ws_size >= need_main) {
    char* wsb = (char*)d_ws;
    float* h1f32 = (float*)wsb;
    char* ub = wsb + H1F32_BYTES;                 // union base
    unsigned short* xsplit = (unsigned short*)ub;
    unsigned short* w1b = (unsigned short*)(ub + XSPL_BYTES);
    float* conv = (float*)ub;                     // aliases xsplit (after l1)
    unsigned short* wp0 = (unsigned short*)(ub + CONV_BYTES);
    unsigned short* wp1 = wp0 + WSPLIT_ELEMS;
    unsigned short* wp2 = wp1 + WSPLIT_ELEMS;
    unsigned int* cntblk = (unsigned int*)(ub + CONV_BYTES + 3 * WSPL_BYTES);
    unsigned int* list1 = cntblk + 4;
    unsigned int* list2 = list1 + REDO_CAP;

    init_cnt_kernel<<<1, 1, 0, stream>>>(cntblk);
    x_split_kernel<<<2304, 256, 0, stream>>>(x, xsplit);
    w1_split_kernel<<<84, 256, 0, stream>>>(W1, w1b);
    w2_split_kernel<<<3528, 256, 0, stream>>>(W2, wp0, wp1, wp2);
    l1_mfma_kernel<<<dim3(3, 15, 64), 256, 0, stream>>>(
        xsplit, w1b, b1, h1f32, cntblk + 0, list1, kp1a, kp1b);
    l1_redo_kernel<<<REDO_CAP, 64, 0, stream>>>(x, W1, b1, h1f32,
                                                cntblk + 0, list1, kp1a, kp1b);
    l2_mfma_kernel<<<dim3(3, 192), 256, 0, stream>>>(h1f32, wp0, wp1, wp2, conv);
    l2_pool_kernel<<<dim3(64, 64), 192, 0, stream>>>(conv, b2, out,
                                                     cntblk + 1, list2, kp2a, kp2b);
    l2_redo_kernel<<<REDO_CAP, 64, 0, stream>>>(h1f32, W2, b2, out,
                                                cntblk + 1, list2, kp2a, kp2b);
  } else {
    // fallback: exact f64 two-stage (R8-verified)
    double* h1 = (double*)d_ws;
    l1_kernel<<<dim3(96, 64, 2), 256, 0, stream>>>(
        x, W1, b1, h1, (float*)0, 1, 0, (unsigned int*)0, kp1a, kp1b);
    l2_kernel_f64<<<dim3(24, 64), 256, 0, stream>>>(h1, W2, b2, out,
                                                    kp2a, kp2b);
  }
}